// Round 1
// baseline (3347.746 us; speedup 1.0000x reference)
//
#include <hip/hip_runtime.h>
#include <hip/hip_bf16.h>

#define NN 50000
#define NE 600000
#define NG 64

// ---------------- degree / norm ----------------
__global__ void k_deg_init(float* deg, int n) {
    int i = blockIdx.x * blockDim.x + threadIdx.x;
    if (i < n) deg[i] = 1.0f;   // self-loop contributes 1 to every node
}

__global__ void k_deg_edges(const int* __restrict__ dst, float* deg, int ne) {
    int e = blockIdx.x * blockDim.x + threadIdx.x;
    if (e < ne) atomicAdd(&deg[dst[e]], 1.0f);
}

__global__ void k_dinv(float* deg, int n) {
    int i = blockIdx.x * blockDim.x + threadIdx.x;
    if (i < n) deg[i] = rsqrtf(deg[i]);   // deg >= 1 always
}

// ---------------- self-loop init: agg[i] = h[i] * dinv[i]^2 ----------------
template<int C>
__global__ void k_selfloop(const float* __restrict__ h, const float* __restrict__ dinv,
                           float* __restrict__ agg, int n) {
    int idx = blockIdx.x * blockDim.x + threadIdx.x;   // float4 index
    int total = n * (C / 4);
    if (idx >= total) return;
    int i = idx / (C / 4);
    float d = dinv[i];
    d = d * d;
    float4 v = ((const float4*)h)[idx];
    v.x *= d; v.y *= d; v.z *= d; v.w *= d;
    ((float4*)agg)[idx] = v;
}

// ---------------- edge aggregation: agg[dst] += h[src] * dinv[s]*dinv[d] ----------------
template<int C>
__global__ __launch_bounds__(256)
void k_edge_agg(const int* __restrict__ src, const int* __restrict__ dst,
                const float* __restrict__ dinv, const float* __restrict__ h,
                float* __restrict__ agg, int ne) {
    constexpr int V = C / 64;   // floats per lane (2 or 4)
    int t = blockIdx.x * blockDim.x + threadIdx.x;
    int e = t >> 6;
    int lane = t & 63;
    if (e >= ne) return;
    int s = src[e], d = dst[e];
    float w = dinv[s] * dinv[d];
    const float* hs = h + (size_t)s * C + lane * V;
    float* ad = agg + (size_t)d * C + lane * V;
    if constexpr (V == 4) {
        float4 v = *(const float4*)hs;
        atomicAdd(ad + 0, v.x * w);
        atomicAdd(ad + 1, v.y * w);
        atomicAdd(ad + 2, v.z * w);
        atomicAdd(ad + 3, v.w * w);
    } else {
        float2 v = *(const float2*)hs;
        atomicAdd(ad + 0, v.x * w);
        atomicAdd(ad + 1, v.y * w);
    }
}

// ---------------- tiled SGEMM, epilogue = relu(acc + bias); optional pool-atomic ----------------
// C[M,N] = relu(A[M,K] @ W[K,N] + b[N]); if POOL, atomicAdd into pool_sums[batch[row]*N+col]
template<bool POOL>
__global__ __launch_bounds__(256)
void k_gemm_fused(const float* __restrict__ A, const float* __restrict__ W,
                  const float* __restrict__ bias,
                  float* __restrict__ out,
                  const int* __restrict__ batch,
                  float* __restrict__ pool_sums,
                  int M, int N, int K) {
    const int BM = 64, BN = 64, BK = 16;
    __shared__ float As[16][64];
    __shared__ float Bs[16][64];
    int tid = threadIdx.x;
    int bm = blockIdx.y * BM, bn = blockIdx.x * BN;
    int tx = tid & 15, ty = tid >> 4;
    float acc[4][4] = {};

    int aRow = tid >> 2, aCol = (tid & 3) * 4;     // A: 64 rows x 16 cols, float4 per thread
    int bRow = tid >> 4, bCol = (tid & 15) * 4;    // B: 16 rows x 64 cols, float4 per thread

    for (int k0 = 0; k0 < K; k0 += BK) {
        int gr = bm + aRow;
        float4 av;
        if (gr < M) av = *(const float4*)(A + (size_t)gr * K + k0 + aCol);
        else        av = make_float4(0.f, 0.f, 0.f, 0.f);
        As[aCol + 0][aRow] = av.x;
        As[aCol + 1][aRow] = av.y;
        As[aCol + 2][aRow] = av.z;
        As[aCol + 3][aRow] = av.w;
        float4 bv = *(const float4*)(W + (size_t)(k0 + bRow) * N + bn + bCol);
        *(float4*)&Bs[bRow][bCol] = bv;
        __syncthreads();
#pragma unroll
        for (int k = 0; k < BK; ++k) {
            float a[4], b[4];
#pragma unroll
            for (int i = 0; i < 4; ++i) a[i] = As[k][ty * 4 + i];
#pragma unroll
            for (int j = 0; j < 4; ++j) b[j] = Bs[k][tx * 4 + j];
#pragma unroll
            for (int i = 0; i < 4; ++i)
#pragma unroll
                for (int j = 0; j < 4; ++j)
                    acc[i][j] += a[i] * b[j];
        }
        __syncthreads();
    }
#pragma unroll
    for (int i = 0; i < 4; ++i) {
        int r = bm + ty * 4 + i;
        if (r >= M) continue;
        int g = POOL ? batch[r] : 0;
#pragma unroll
        for (int j = 0; j < 4; ++j) {
            int c = bn + tx * 4 + j;
            float v = fmaxf(acc[i][j] + bias[c], 0.0f);
            if (POOL) {
                atomicAdd(&pool_sums[g * N + c], v);
            } else {
                out[(size_t)r * N + c] = v;
            }
        }
    }
}

// ---------------- pool helpers ----------------
__global__ void k_zero(float* p, int n) {
    int i = blockIdx.x * blockDim.x + threadIdx.x;
    if (i < n) p[i] = 0.0f;
}

__global__ void k_counts(const int* __restrict__ batch, float* counts, int n) {
    int i = blockIdx.x * blockDim.x + threadIdx.x;
    if (i < n) atomicAdd(&counts[batch[i]], 1.0f);
}

// ---------------- dense head: g=sums/cnt; relu(g@W3+b3); @W4+b4 ----------------
__global__ __launch_bounds__(128)
void k_dense(const float* __restrict__ sums, const float* __restrict__ counts,
             const float* __restrict__ W3, const float* __restrict__ b3,
             const float* __restrict__ W4, const float* __restrict__ b4,
             float* __restrict__ out) {
    __shared__ float g[256];
    __shared__ float hid[128];
    int gi = blockIdx.x;
    int t = threadIdx.x;
    float inv = 1.0f / fmaxf(counts[gi], 1.0f);
    for (int c = t; c < 256; c += 128) g[c] = sums[gi * 256 + c] * inv;
    __syncthreads();
    float acc = b3[t];
    for (int k = 0; k < 256; ++k) acc += g[k] * W3[k * 128 + t];
    hid[t] = fmaxf(acc, 0.0f);
    __syncthreads();
    if (t < 10) {
        float o = b4[t];
        for (int k = 0; k < 128; ++k) o += hid[k] * W4[k * 10 + t];
        out[gi * 10 + t] = o;
    }
}

extern "C" void kernel_launch(void* const* d_in, const int* in_sizes, int n_in,
                              void* d_out, int out_size, void* d_ws, size_t ws_size,
                              hipStream_t stream) {
    const float* x   = (const float*)d_in[0];
    const int*  eidx = (const int*)d_in[1];    // [2, NE] row-major
    const int*  batch= (const int*)d_in[2];
    const float* W1 = (const float*)d_in[3];
    const float* b1 = (const float*)d_in[4];
    const float* W2 = (const float*)d_in[5];
    const float* b2 = (const float*)d_in[6];
    const float* W3 = (const float*)d_in[7];
    const float* b3 = (const float*)d_in[8];
    const float* W4 = (const float*)d_in[9];
    const float* b4 = (const float*)d_in[10];
    float* out = (float*)d_out;

    const int N = NN, E = NE, G = NG;
    const int* src = eidx;
    const int* dst = eidx + E;

    float* aggx   = (float*)d_ws;                       // N*128
    float* h1     = aggx + (size_t)N * 128;             // N*256
    float* agg2   = h1 + (size_t)N * 256;               // N*256
    float* dinv   = agg2 + (size_t)N * 256;             // N   (deg, then rsqrt in place)
    float* sums   = dinv + N;                           // G*256
    float* counts = sums + (size_t)G * 256;             // G

    // degrees -> dinv
    k_deg_init<<<(N + 255) / 256, 256, 0, stream>>>(dinv, N);
    k_deg_edges<<<(E + 255) / 256, 256, 0, stream>>>(dst, dinv, E);
    k_dinv<<<(N + 255) / 256, 256, 0, stream>>>(dinv, N);

    // conv1: aggregate x first (128 ch), then GEMM(K=128) with bias+relu
    k_selfloop<128><<<(N * 32 + 255) / 256, 256, 0, stream>>>(x, dinv, aggx, N);
    k_edge_agg<128><<<(E + 3) / 4, 256, 0, stream>>>(src, dst, dinv, x, aggx, E);
    dim3 gemm_grid(256 / 64, (N + 63) / 64);
    k_gemm_fused<false><<<gemm_grid, 256, 0, stream>>>(aggx, W1, b1, h1, nullptr, nullptr, N, 256, 128);

    // conv2: aggregate h1 (256 ch), then GEMM(K=256) with bias+relu fused into pool
    k_selfloop<256><<<(N * 64 + 255) / 256, 256, 0, stream>>>(h1, dinv, agg2, N);
    k_edge_agg<256><<<(E + 3) / 4, 256, 0, stream>>>(src, dst, dinv, h1, agg2, E);

    k_zero<<<(G * 256 + G + 255) / 256, 256, 0, stream>>>(sums, G * 256 + G);
    k_counts<<<(N + 255) / 256, 256, 0, stream>>>(batch, counts, N);
    k_gemm_fused<true><<<gemm_grid, 256, 0, stream>>>(agg2, W2, b2, nullptr, batch, sums, N, 256, 256);

    // dense head
    k_dense<<<G, 128, 0, stream>>>(sums, counts, W3, b3, W4, b4, out);
}

// Round 2
// 1104.214 us; speedup vs baseline: 3.0318x; 3.0318x over previous
//
#include <hip/hip_runtime.h>
#include <hip/hip_bf16.h>

#define NN 50000
#define NE 600000
#define NG 64

// ---------------- CSR build ----------------
__global__ void k_zero_int(int* p, int n) {
    int i = blockIdx.x * blockDim.x + threadIdx.x;
    if (i < n) p[i] = 0;
}

__global__ void k_hist(const int* __restrict__ dst, int* __restrict__ cnt, int ne) {
    int e = blockIdx.x * blockDim.x + threadIdx.x;
    if (e < ne) atomicAdd(&cnt[dst[e]], 1);
}

// single-block exclusive scan over cnt[0..n) -> rowptr & cursor; also dinv = rsqrt(1+cnt)
__global__ __launch_bounds__(1024)
void k_scan(const int* __restrict__ cnt, int* __restrict__ rowptr, int* __restrict__ cursor,
            float* __restrict__ dinv, int n) {
    __shared__ int buf[1024];
    __shared__ int carry;
    int t = threadIdx.x;
    if (t == 0) carry = 0;
    __syncthreads();
    for (int base = 0; base < n; base += 1024) {
        int i = base + t;
        int v = (i < n) ? cnt[i] : 0;
        int carry_in = carry;
        buf[t] = v;
        __syncthreads();
#pragma unroll
        for (int off = 1; off < 1024; off <<= 1) {
            int x = (t >= off) ? buf[t - off] : 0;
            __syncthreads();
            buf[t] += x;
            __syncthreads();
        }
        if (i < n) {
            int excl = carry_in + buf[t] - v;
            rowptr[i] = excl;
            cursor[i] = excl;
            dinv[i] = rsqrtf(1.0f + (float)v);
        }
        int total = buf[1023];
        __syncthreads();
        if (t == 0) carry += total;
        __syncthreads();
    }
    if (t == 0) rowptr[n] = carry;
}

__global__ void k_fill(const int* __restrict__ src, const int* __restrict__ dst,
                       int* __restrict__ cursor, int* __restrict__ csr_src, int ne) {
    int e = blockIdx.x * blockDim.x + threadIdx.x;
    if (e < ne) {
        int pos = atomicAdd(&cursor[dst[e]], 1);
        csr_src[pos] = src[e];
    }
}

// ---------------- gather aggregation ----------------
// agg[d] = dinv[d] * ( sum_{s in in(d)} dinv[s]*h[s]  +  dinv[d]*h[d] )
template<int C>
__global__ __launch_bounds__(256)
void k_agg_gather(const int* __restrict__ rowptr, const int* __restrict__ csr_src,
                  const float* __restrict__ dinv, const float* __restrict__ h,
                  float* __restrict__ agg, int n) {
    constexpr int V = C / 64;   // floats per lane (2 or 4)
    int node = (blockIdx.x * blockDim.x + threadIdx.x) >> 6;
    int lane = threadIdx.x & 63;
    if (node >= n) return;
    int beg = rowptr[node], end = rowptr[node + 1];
    float di = dinv[node];
    float acc[V];
    {   // self loop term: dinv[d]*h[d]
        const float* hw = h + (size_t)node * C + lane * V;
        if constexpr (V == 4) {
            float4 v = *(const float4*)hw;
            acc[0] = v.x * di; acc[1] = v.y * di; acc[2] = v.z * di; acc[3] = v.w * di;
        } else {
            float2 v = *(const float2*)hw;
            acc[0] = v.x * di; acc[1] = v.y * di;
        }
    }
    int j = beg;
    for (; j + 1 < end; j += 2) {
        int s0 = csr_src[j], s1 = csr_src[j + 1];
        float w0 = dinv[s0], w1 = dinv[s1];
        const float* p0 = h + (size_t)s0 * C + lane * V;
        const float* p1 = h + (size_t)s1 * C + lane * V;
        if constexpr (V == 4) {
            float4 v0 = *(const float4*)p0;
            float4 v1 = *(const float4*)p1;
            acc[0] += v0.x * w0 + v1.x * w1;
            acc[1] += v0.y * w0 + v1.y * w1;
            acc[2] += v0.z * w0 + v1.z * w1;
            acc[3] += v0.w * w0 + v1.w * w1;
        } else {
            float2 v0 = *(const float2*)p0;
            float2 v1 = *(const float2*)p1;
            acc[0] += v0.x * w0 + v1.x * w1;
            acc[1] += v0.y * w0 + v1.y * w1;
        }
    }
    if (j < end) {
        int s0 = csr_src[j];
        float w0 = dinv[s0];
        const float* p0 = h + (size_t)s0 * C + lane * V;
        if constexpr (V == 4) {
            float4 v0 = *(const float4*)p0;
            acc[0] += v0.x * w0; acc[1] += v0.y * w0; acc[2] += v0.z * w0; acc[3] += v0.w * w0;
        } else {
            float2 v0 = *(const float2*)p0;
            acc[0] += v0.x * w0; acc[1] += v0.y * w0;
        }
    }
    float* ap = agg + (size_t)node * C + lane * V;
    if constexpr (V == 4) {
        float4 o; o.x = acc[0] * di; o.y = acc[1] * di; o.z = acc[2] * di; o.w = acc[3] * di;
        *(float4*)ap = o;
    } else {
        float2 o; o.x = acc[0] * di; o.y = acc[1] * di;
        *(float2*)ap = o;
    }
}

// ---------------- tiled SGEMM, epilogue = relu(acc + bias); optional pool-atomic ----------------
template<bool POOL>
__global__ __launch_bounds__(256)
void k_gemm_fused(const float* __restrict__ A, const float* __restrict__ W,
                  const float* __restrict__ bias,
                  float* __restrict__ out,
                  const int* __restrict__ batch,
                  float* __restrict__ pool_sums,
                  int M, int N, int K) {
    const int BM = 64, BN = 64, BK = 16;
    __shared__ float As[16][64];
    __shared__ float Bs[16][64];
    int tid = threadIdx.x;
    int bm = blockIdx.y * BM, bn = blockIdx.x * BN;
    int tx = tid & 15, ty = tid >> 4;
    float acc[4][4] = {};

    int aRow = tid >> 2, aCol = (tid & 3) * 4;     // A: 64 rows x 16 cols, float4 per thread
    int bRow = tid >> 4, bCol = (tid & 15) * 4;    // B: 16 rows x 64 cols, float4 per thread

    for (int k0 = 0; k0 < K; k0 += BK) {
        int gr = bm + aRow;
        float4 av;
        if (gr < M) av = *(const float4*)(A + (size_t)gr * K + k0 + aCol);
        else        av = make_float4(0.f, 0.f, 0.f, 0.f);
        As[aCol + 0][aRow] = av.x;
        As[aCol + 1][aRow] = av.y;
        As[aCol + 2][aRow] = av.z;
        As[aCol + 3][aRow] = av.w;
        float4 bv = *(const float4*)(W + (size_t)(k0 + bRow) * N + bn + bCol);
        *(float4*)&Bs[bRow][bCol] = bv;
        __syncthreads();
#pragma unroll
        for (int k = 0; k < BK; ++k) {
            float a[4], b[4];
#pragma unroll
            for (int i = 0; i < 4; ++i) a[i] = As[k][ty * 4 + i];
#pragma unroll
            for (int j = 0; j < 4; ++j) b[j] = Bs[k][tx * 4 + j];
#pragma unroll
            for (int i = 0; i < 4; ++i)
#pragma unroll
                for (int j = 0; j < 4; ++j)
                    acc[i][j] += a[i] * b[j];
        }
        __syncthreads();
    }
#pragma unroll
    for (int i = 0; i < 4; ++i) {
        int r = bm + ty * 4 + i;
        if (r >= M) continue;
        int g = POOL ? batch[r] : 0;
#pragma unroll
        for (int j = 0; j < 4; ++j) {
            int c = bn + tx * 4 + j;
            float v = fmaxf(acc[i][j] + bias[c], 0.0f);
            if (POOL) {
                atomicAdd(&pool_sums[g * N + c], v);
            } else {
                out[(size_t)r * N + c] = v;
            }
        }
    }
}

// ---------------- pool helpers ----------------
__global__ void k_zero(float* p, int n) {
    int i = blockIdx.x * blockDim.x + threadIdx.x;
    if (i < n) p[i] = 0.0f;
}

__global__ void k_counts(const int* __restrict__ batch, float* counts, int n) {
    int i = blockIdx.x * blockDim.x + threadIdx.x;
    if (i < n) atomicAdd(&counts[batch[i]], 1.0f);
}

// ---------------- dense head: g=sums/cnt; relu(g@W3+b3); @W4+b4 ----------------
__global__ __launch_bounds__(128)
void k_dense(const float* __restrict__ sums, const float* __restrict__ counts,
             const float* __restrict__ W3, const float* __restrict__ b3,
             const float* __restrict__ W4, const float* __restrict__ b4,
             float* __restrict__ out) {
    __shared__ float g[256];
    __shared__ float hid[128];
    int gi = blockIdx.x;
    int t = threadIdx.x;
    float inv = 1.0f / fmaxf(counts[gi], 1.0f);
    for (int c = t; c < 256; c += 128) g[c] = sums[gi * 256 + c] * inv;
    __syncthreads();
    float acc = b3[t];
    for (int k = 0; k < 256; ++k) acc += g[k] * W3[k * 128 + t];
    hid[t] = fmaxf(acc, 0.0f);
    __syncthreads();
    if (t < 10) {
        float o = b4[t];
        for (int k = 0; k < 128; ++k) o += hid[k] * W4[k * 10 + t];
        out[gi * 10 + t] = o;
    }
}

extern "C" void kernel_launch(void* const* d_in, const int* in_sizes, int n_in,
                              void* d_out, int out_size, void* d_ws, size_t ws_size,
                              hipStream_t stream) {
    const float* x   = (const float*)d_in[0];
    const int*  eidx = (const int*)d_in[1];    // [2, NE]
    const int*  batch= (const int*)d_in[2];
    const float* W1 = (const float*)d_in[3];
    const float* b1 = (const float*)d_in[4];
    const float* W2 = (const float*)d_in[5];
    const float* b2 = (const float*)d_in[6];
    const float* W3 = (const float*)d_in[7];
    const float* b3 = (const float*)d_in[8];
    const float* W4 = (const float*)d_in[9];
    const float* b4 = (const float*)d_in[10];
    float* out = (float*)d_out;

    const int N = NN, E = NE, G = NG;
    const int* src = eidx;
    const int* dst = eidx + E;

    // workspace layout
    float* aggx   = (float*)d_ws;                       // N*128 f
    float* h1     = aggx + (size_t)N * 128;             // N*256 f
    float* agg2   = h1 + (size_t)N * 256;               // N*256 f
    float* dinv   = agg2 + (size_t)N * 256;             // N f
    float* sums   = dinv + N;                           // G*256 f
    float* counts = sums + (size_t)G * 256;             // G f
    int*   cnt    = (int*)(counts + G);                 // N i
    int*   rowptr = cnt + N;                            // N+1 i
    int*   cursor = rowptr + N + 1;                     // N i
    int*   csr_src= cursor + N;                         // E i

    // CSR build + dinv
    k_zero_int<<<(N + 255) / 256, 256, 0, stream>>>(cnt, N);
    k_hist<<<(E + 255) / 256, 256, 0, stream>>>(dst, cnt, E);
    k_scan<<<1, 1024, 0, stream>>>(cnt, rowptr, cursor, dinv, N);
    k_fill<<<(E + 255) / 256, 256, 0, stream>>>(src, dst, cursor, csr_src, E);

    // conv1: aggregate x (128 ch) by gather, then GEMM(K=128) with bias+relu
    k_agg_gather<128><<<(N + 3) / 4, 256, 0, stream>>>(rowptr, csr_src, dinv, x, aggx, N);
    dim3 gemm_grid(256 / 64, (N + 63) / 64);
    k_gemm_fused<false><<<gemm_grid, 256, 0, stream>>>(aggx, W1, b1, h1, nullptr, nullptr, N, 256, 128);

    // conv2: aggregate h1 (256 ch) by gather, then GEMM(K=256) fused into pool
    k_agg_gather<256><<<(N + 3) / 4, 256, 0, stream>>>(rowptr, csr_src, dinv, h1, agg2, N);

    k_zero<<<(G * 256 + G + 255) / 256, 256, 0, stream>>>(sums, G * 256 + G);
    k_counts<<<(N + 255) / 256, 256, 0, stream>>>(batch, counts, N);
    k_gemm_fused<true><<<gemm_grid, 256, 0, stream>>>(agg2, W2, b2, nullptr, batch, sums, N, 256, 256);

    // dense head
    k_dense<<<G, 128, 0, stream>>>(sums, counts, W3, b3, W4, b4, out);
}

// Round 3
// 727.108 us; speedup vs baseline: 4.6042x; 1.5186x over previous
//
#include <hip/hip_runtime.h>

typedef unsigned short u16;
typedef unsigned int u32;
typedef __attribute__((ext_vector_type(8))) short s16x8;
typedef __attribute__((ext_vector_type(4))) float f32x4;

#define NN 50000
#define NE 600000
#define NG 64

__device__ __forceinline__ u16 f2bf(float f) {
    u32 u = __float_as_uint(f);
    u32 r = (u + 0x7fffu + ((u >> 16) & 1u)) >> 16;
    return (u16)r;
}
__device__ __forceinline__ float bf2f(u16 h) {
    return __uint_as_float(((u32)h) << 16);
}
__device__ __forceinline__ void gll16(const void* g, void* l) {
    __builtin_amdgcn_global_load_lds((const __attribute__((address_space(1))) u32*)g,
                                     (__attribute__((address_space(3))) u32*)l, 16, 0, 0);
}

// ---------------- CSR build ----------------
__global__ void k_zero_int(int* p, int n) {
    int i = blockIdx.x * blockDim.x + threadIdx.x;
    if (i < n) p[i] = 0;
}

__global__ void k_hist(const int* __restrict__ dst, int* __restrict__ cnt, int ne) {
    int e = blockIdx.x * blockDim.x + threadIdx.x;
    if (e < ne) atomicAdd(&cnt[dst[e]], 1);
}

// single-block exclusive scan; cursor may alias cnt (written after cnt[i] is read)
__global__ __launch_bounds__(1024)
void k_scan(const int* __restrict__ cnt, int* __restrict__ rowptr, int* __restrict__ cursor,
            float* __restrict__ dinv, int n) {
    __shared__ int buf[1024];
    __shared__ int carry;
    int t = threadIdx.x;
    if (t == 0) carry = 0;
    __syncthreads();
    for (int base = 0; base < n; base += 1024) {
        int i = base + t;
        int v = (i < n) ? cnt[i] : 0;
        int carry_in = carry;
        buf[t] = v;
        __syncthreads();
#pragma unroll
        for (int off = 1; off < 1024; off <<= 1) {
            int x = (t >= off) ? buf[t - off] : 0;
            __syncthreads();
            buf[t] += x;
            __syncthreads();
        }
        if (i < n) {
            int excl = carry_in + buf[t] - v;
            rowptr[i] = excl;
            cursor[i] = excl;
            dinv[i] = rsqrtf(1.0f + (float)v);
        }
        int total = buf[1023];
        __syncthreads();
        if (t == 0) carry += total;
        __syncthreads();
    }
    if (t == 0) rowptr[n] = carry;
}

__global__ void k_fill(const int* __restrict__ src, const int* __restrict__ dst,
                       int* __restrict__ cursor, int* __restrict__ csr_src, int ne) {
    int e = blockIdx.x * blockDim.x + threadIdx.x;
    if (e < ne) {
        int pos = atomicAdd(&cursor[dst[e]], 1);
        csr_src[pos] = src[e];
    }
}

// ---------------- weight transpose + bf16 split: Wt[n][k] = W[k][n] ----------------
__global__ void k_wsplit(const float* __restrict__ W, u16* __restrict__ Whi, u16* __restrict__ Wlo,
                         int K, int N) {
    int idx = blockIdx.x * blockDim.x + threadIdx.x;
    if (idx >= K * N) return;
    int n = idx / K, k = idx - n * K;
    float w = W[(size_t)k * N + n];
    u16 hi = f2bf(w);
    u16 lo = f2bf(w - bf2f(hi));
    Whi[idx] = hi;
    Wlo[idx] = lo;
}

// ---------------- gather aggregation -> bf16 hi/lo ----------------
// agg[d] = dinv[d] * ( sum_{s in in(d)} dinv[s]*h[s] + dinv[d]*h[d] )
template<int C>
__global__ __launch_bounds__(256)
void k_agg_gather(const int* __restrict__ rowptr, const int* __restrict__ csr_src,
                  const float* __restrict__ dinv, const float* __restrict__ h,
                  u16* __restrict__ out_hi, u16* __restrict__ out_lo, int n) {
    constexpr int V = C / 64;   // floats per lane (2 or 4)
    int node = (blockIdx.x * blockDim.x + threadIdx.x) >> 6;
    int lane = threadIdx.x & 63;
    if (node >= n) return;
    int beg = rowptr[node], end = rowptr[node + 1];
    float di = dinv[node];
    float acc[V];
    {
        const float* hw = h + (size_t)node * C + lane * V;
        if constexpr (V == 4) {
            float4 v = *(const float4*)hw;
            acc[0] = v.x * di; acc[1] = v.y * di; acc[2] = v.z * di; acc[3] = v.w * di;
        } else {
            float2 v = *(const float2*)hw;
            acc[0] = v.x * di; acc[1] = v.y * di;
        }
    }
    int j = beg;
    for (; j + 1 < end; j += 2) {
        int s0 = csr_src[j], s1 = csr_src[j + 1];
        float w0 = dinv[s0], w1 = dinv[s1];
        const float* p0 = h + (size_t)s0 * C + lane * V;
        const float* p1 = h + (size_t)s1 * C + lane * V;
        if constexpr (V == 4) {
            float4 v0 = *(const float4*)p0;
            float4 v1 = *(const float4*)p1;
            acc[0] += v0.x * w0 + v1.x * w1;
            acc[1] += v0.y * w0 + v1.y * w1;
            acc[2] += v0.z * w0 + v1.z * w1;
            acc[3] += v0.w * w0 + v1.w * w1;
        } else {
            float2 v0 = *(const float2*)p0;
            float2 v1 = *(const float2*)p1;
            acc[0] += v0.x * w0 + v1.x * w1;
            acc[1] += v0.y * w0 + v1.y * w1;
        }
    }
    if (j < end) {
        int s0 = csr_src[j];
        float w0 = dinv[s0];
        const float* p0 = h + (size_t)s0 * C + lane * V;
        if constexpr (V == 4) {
            float4 v0 = *(const float4*)p0;
            acc[0] += v0.x * w0; acc[1] += v0.y * w0; acc[2] += v0.z * w0; acc[3] += v0.w * w0;
        } else {
            float2 v0 = *(const float2*)p0;
            acc[0] += v0.x * w0; acc[1] += v0.y * w0;
        }
    }
    u16 hi[V], lo[V];
#pragma unroll
    for (int i = 0; i < V; ++i) {
        float a = acc[i] * di;
        hi[i] = f2bf(a);
        lo[i] = f2bf(a - bf2f(hi[i]));
    }
    if constexpr (V == 4) {
        uint2 ph, pl;
        ph.x = (u32)hi[0] | ((u32)hi[1] << 16); ph.y = (u32)hi[2] | ((u32)hi[3] << 16);
        pl.x = (u32)lo[0] | ((u32)lo[1] << 16); pl.y = (u32)lo[2] | ((u32)lo[3] << 16);
        ((uint2*)out_hi)[(size_t)node * 64 + lane] = ph;
        ((uint2*)out_lo)[(size_t)node * 64 + lane] = pl;
    } else {
        ((u32*)out_hi)[(size_t)node * 64 + lane] = (u32)hi[0] | ((u32)hi[1] << 16);
        ((u32*)out_lo)[(size_t)node * 64 + lane] = (u32)lo[0] | ((u32)lo[1] << 16);
    }
}

// ---------------- MFMA GEMM: C = relu(A@W + b), A split-bf16 [M][K], Wt split-bf16 [256][K] ----------------
// BM=BN=128, BK=32, 4 waves each 64x64. POOL: atomicAdd run-length-compressed into pool[batch[row]*256+col]
template<bool POOL>
__global__ __launch_bounds__(256)
void k_gemm_mfma(const u16* __restrict__ Ahi, const u16* __restrict__ Alo,
                 const u16* __restrict__ Bhi, const u16* __restrict__ Blo,
                 const float* __restrict__ bias, float* __restrict__ out,
                 const int* __restrict__ batch, float* __restrict__ pool,
                 int M, int K) {
    __shared__ u16 lds[4][128 * 32];   // Ahi, Alo, Bhi, Blo tiles: [128 rows][32 k] bf16
    const int tid = threadIdx.x, lane = tid & 63, wid = tid >> 6;
    const int bm = blockIdx.y * 128, bn = blockIdx.x * 128;
    const int wr = (wid >> 1) * 64, wc = (wid & 1) * 64;
    const int lr = lane & 15, kg = lane >> 4;
    const int arow = lane >> 2;          // row within 16-row chunk
    const int acol = (lane & 3) * 8;     // bf16 col offset within 32-wide tile

    f32x4 acc[4][4];
#pragma unroll
    for (int i = 0; i < 4; ++i)
#pragma unroll
        for (int j = 0; j < 4; ++j) acc[i][j] = (f32x4){0.f, 0.f, 0.f, 0.f};

    for (int k0 = 0; k0 < K; k0 += 32) {
        // stage 32 chunks of 1KB: chunk c -> lds[c>>3] rows 16*(c&7)..+15
#pragma unroll
        for (int i = 0; i < 8; ++i) {
            int c = wid * 8 + i;
            int buf = c >> 3, cc = c & 7;
            const u16* gb = (buf == 0) ? Ahi : (buf == 1) ? Alo : (buf == 2) ? Bhi : Blo;
            int row;
            if (buf < 2) { row = bm + cc * 16 + arow; if (row >= M) row = M - 1; }
            else         { row = bn + cc * 16 + arow; }
            const u16* gp = gb + (size_t)row * K + k0 + acol;
            gll16(gp, &lds[buf][cc * 512]);
        }
        __syncthreads();

        s16x8 ahi[4], alo[4];
#pragma unroll
        for (int fm = 0; fm < 4; ++fm) {
            int r = wr + fm * 16 + lr;
            ahi[fm] = *(const s16x8*)&lds[0][r * 32 + kg * 8];
            alo[fm] = *(const s16x8*)&lds[1][r * 32 + kg * 8];
        }
#pragma unroll
        for (int fn = 0; fn < 4; ++fn) {
            int cidx = wc + fn * 16 + lr;
            s16x8 bhi = *(const s16x8*)&lds[2][cidx * 32 + kg * 8];
            s16x8 blo = *(const s16x8*)&lds[3][cidx * 32 + kg * 8];
#pragma unroll
            for (int fm = 0; fm < 4; ++fm) {
                acc[fm][fn] = __builtin_amdgcn_mfma_f32_16x16x32_bf16(ahi[fm], bhi, acc[fm][fn], 0, 0, 0);
                acc[fm][fn] = __builtin_amdgcn_mfma_f32_16x16x32_bf16(ahi[fm], blo, acc[fm][fn], 0, 0, 0);
                acc[fm][fn] = __builtin_amdgcn_mfma_f32_16x16x32_bf16(alo[fm], bhi, acc[fm][fn], 0, 0, 0);
            }
        }
        __syncthreads();
    }

    // epilogue: D row = bm + wr + fm*16 + kg*4 + r ; col = bn + wc + fn*16 + lr
#pragma unroll
    for (int fn = 0; fn < 4; ++fn) {
        int col = bn + wc + fn * 16 + lr;
        float bv = bias[col];
        if (!POOL) {
#pragma unroll
            for (int fm = 0; fm < 4; ++fm) {
                int rbase = bm + wr + fm * 16 + kg * 4;
#pragma unroll
                for (int r = 0; r < 4; ++r) {
                    int row = rbase + r;
                    if (row < M)
                        out[(size_t)row * 256 + col] = fmaxf(acc[fm][fn][r] + bv, 0.f);
                }
            }
        } else {
            int gcur = -1;
            float run = 0.f;
#pragma unroll
            for (int fm = 0; fm < 4; ++fm) {
                int rbase = bm + wr + fm * 16 + kg * 4;
#pragma unroll
                for (int r = 0; r < 4; ++r) {
                    int row = rbase + r;
                    if (row < M) {
                        int g = batch[row];
                        float v = fmaxf(acc[fm][fn][r] + bv, 0.f);
                        if (g != gcur) {
                            if (gcur >= 0) atomicAdd(&pool[gcur * 256 + col], run);
                            gcur = g;
                            run = 0.f;
                        }
                        run += v;
                    }
                }
            }
            if (gcur >= 0) atomicAdd(&pool[gcur * 256 + col], run);
        }
    }
}

// ---------------- pool helpers ----------------
__global__ void k_zero(float* p, int n) {
    int i = blockIdx.x * blockDim.x + threadIdx.x;
    if (i < n) p[i] = 0.0f;
}

__global__ void k_counts(const int* __restrict__ batch, float* counts, int n) {
    int i = blockIdx.x * blockDim.x + threadIdx.x;
    if (i < n) atomicAdd(&counts[batch[i]], 1.0f);
}

// ---------------- dense head ----------------
__global__ __launch_bounds__(128)
void k_dense(const float* __restrict__ sums, const float* __restrict__ counts,
             const float* __restrict__ W3, const float* __restrict__ b3,
             const float* __restrict__ W4, const float* __restrict__ b4,
             float* __restrict__ out) {
    __shared__ float g[256];
    __shared__ float hid[128];
    int gi = blockIdx.x;
    int t = threadIdx.x;
    float inv = 1.0f / fmaxf(counts[gi], 1.0f);
    for (int c = t; c < 256; c += 128) g[c] = sums[gi * 256 + c] * inv;
    __syncthreads();
    float acc = b3[t];
    for (int k = 0; k < 256; ++k) acc += g[k] * W3[k * 128 + t];
    hid[t] = fmaxf(acc, 0.0f);
    __syncthreads();
    if (t < 10) {
        float o = b4[t];
        for (int k = 0; k < 128; ++k) o += hid[k] * W4[k * 10 + t];
        out[gi * 10 + t] = o;
    }
}

extern "C" void kernel_launch(void* const* d_in, const int* in_sizes, int n_in,
                              void* d_out, int out_size, void* d_ws, size_t ws_size,
                              hipStream_t stream) {
    const float* x   = (const float*)d_in[0];
    const int*  eidx = (const int*)d_in[1];    // [2, NE]
    const int*  batch= (const int*)d_in[2];
    const float* W1 = (const float*)d_in[3];
    const float* b1 = (const float*)d_in[4];
    const float* W2 = (const float*)d_in[5];
    const float* b2 = (const float*)d_in[6];
    const float* W3 = (const float*)d_in[7];
    const float* b3 = (const float*)d_in[8];
    const float* W4 = (const float*)d_in[9];
    const float* b4 = (const float*)d_in[10];
    float* out = (float*)d_out;

    const int N = NN, E = NE, G = NG;
    const int* src = eidx;
    const int* dst = eidx + E;

    // workspace layout (256B-aligned slices)
    char* p = (char*)d_ws;
    auto alloc = [&](size_t bytes) { char* r = p; p += (bytes + 255) & ~(size_t)255; return r; };
    float* h1     = (float*)alloc((size_t)N * 256 * 4);
    float* dinv   = (float*)alloc((size_t)N * 4);
    float* sums   = (float*)alloc((size_t)G * 256 * 4);
    float* counts = (float*)alloc((size_t)G * 4);
    int*   cnt    = (int*)alloc((size_t)N * 4);        // reused as cursor after scan
    int*   rowptr = (int*)alloc((size_t)(N + 1) * 4);
    int*   csr    = (int*)alloc((size_t)E * 4);
    u16*   axhi   = (u16*)alloc((size_t)N * 128 * 2);
    u16*   axlo   = (u16*)alloc((size_t)N * 128 * 2);
    u16*   a2hi   = (u16*)alloc((size_t)N * 256 * 2);
    u16*   a2lo   = (u16*)alloc((size_t)N * 256 * 2);
    u16*   w1hi   = (u16*)alloc((size_t)256 * 128 * 2);
    u16*   w1lo   = (u16*)alloc((size_t)256 * 128 * 2);
    u16*   w2hi   = (u16*)alloc((size_t)256 * 256 * 2);
    u16*   w2lo   = (u16*)alloc((size_t)256 * 256 * 2);
    int*   cursor = cnt;

    // CSR build + dinv
    k_zero_int<<<(N + 255) / 256, 256, 0, stream>>>(cnt, N);
    k_hist<<<(E + 255) / 256, 256, 0, stream>>>(dst, cnt, E);
    k_scan<<<1, 1024, 0, stream>>>(cnt, rowptr, cursor, dinv, N);
    k_fill<<<(E + 255) / 256, 256, 0, stream>>>(src, dst, cursor, csr, E);

    // weight transpose+split
    k_wsplit<<<(128 * 256 + 255) / 256, 256, 0, stream>>>(W1, w1hi, w1lo, 128, 256);
    k_wsplit<<<(256 * 256 + 255) / 256, 256, 0, stream>>>(W2, w2hi, w2lo, 256, 256);

    // conv1: gather-aggregate x (128ch) -> split bf16, then MFMA GEMM K=128 -> h1 (fp32, relu+bias)
    k_agg_gather<128><<<(N + 3) / 4, 256, 0, stream>>>(rowptr, csr, dinv, x, axhi, axlo, N);
    dim3 ggrid(2, (N + 127) / 128);
    k_gemm_mfma<false><<<ggrid, 256, 0, stream>>>(axhi, axlo, w1hi, w1lo, b1, h1,
                                                  nullptr, nullptr, N, 128);

    // conv2: gather-aggregate h1 (256ch) -> split bf16, then MFMA GEMM K=256 fused into pool
    k_agg_gather<256><<<(N + 3) / 4, 256, 0, stream>>>(rowptr, csr, dinv, h1, a2hi, a2lo, N);
    k_zero<<<(G * 256 + G + 255) / 256, 256, 0, stream>>>(sums, G * 256 + G);
    k_counts<<<(N + 255) / 256, 256, 0, stream>>>(batch, counts, N);
    k_gemm_mfma<true><<<ggrid, 256, 0, stream>>>(a2hi, a2lo, w2hi, w2lo, b2, nullptr,
                                                 batch, sums, N, 256);

    // dense head
    k_dense<<<G, 128, 0, stream>>>(sums, counts, W3, b3, W4, b4, out);
}

// Round 4
// 343.093 us; speedup vs baseline: 9.7576x; 2.1193x over previous
//
#include <hip/hip_runtime.h>

typedef unsigned short u16;
typedef unsigned int u32;
typedef __attribute__((ext_vector_type(8))) short s16x8;
typedef __attribute__((ext_vector_type(4))) float f32x4;

#define NN 50000
#define NE 600000
#define NG 64

__device__ __forceinline__ u16 f2bf(float f) {
    u32 u = __float_as_uint(f);
    u32 r = (u + 0x7fffu + ((u >> 16) & 1u)) >> 16;
    return (u16)r;
}
__device__ __forceinline__ float bf2f(u16 h) {
    return __uint_as_float(((u32)h) << 16);
}
__device__ __forceinline__ void gll16(const void* g, void* l) {
    __builtin_amdgcn_global_load_lds((const __attribute__((address_space(1))) u32*)g,
                                     (__attribute__((address_space(3))) u32*)l, 16, 0, 0);
}

// ---------------- CSR build ----------------
__global__ void k_zero_int(int* p, int n) {
    int i = blockIdx.x * blockDim.x + threadIdx.x;
    if (i < n) p[i] = 0;
}

__global__ void k_hist(const int* __restrict__ dst, int* __restrict__ cnt, int ne) {
    int e = blockIdx.x * blockDim.x + threadIdx.x;
    if (e < ne) atomicAdd(&cnt[dst[e]], 1);
}

// ---- 3-phase shuffle scan: bsum per block, scan partials, per-block exclusive ----
__global__ __launch_bounds__(256)
void k_scan1(const int* __restrict__ cnt, int* __restrict__ bsum, int n) {
    int i = blockIdx.x * 256 + threadIdx.x;
    int v = (i < n) ? cnt[i] : 0;
#pragma unroll
    for (int off = 32; off > 0; off >>= 1) v += __shfl_down(v, off, 64);
    __shared__ int ws[4];
    int lane = threadIdx.x & 63, w = threadIdx.x >> 6;
    if (lane == 0) ws[w] = v;
    __syncthreads();
    if (threadIdx.x == 0) bsum[blockIdx.x] = ws[0] + ws[1] + ws[2] + ws[3];
}

// single block, 256 threads, nb <= 256: exclusive scan of bsum in place
__global__ __launch_bounds__(256)
void k_scan2(int* __restrict__ bsum, int nb) {
    int t = threadIdx.x;
    int v = (t < nb) ? bsum[t] : 0;
    int lane = t & 63, w = t >> 6;
    int inc = v;
#pragma unroll
    for (int off = 1; off < 64; off <<= 1) {
        int x = __shfl_up(inc, off, 64);
        if (lane >= off) inc += x;
    }
    __shared__ int wtot[4];
    if (lane == 63) wtot[w] = inc;
    __syncthreads();
    int wo = 0;
    for (int j = 0; j < w; ++j) wo += wtot[j];
    if (t < nb) bsum[t] = wo + inc - v;   // exclusive
}

// per-block exclusive scan + boff; writes rowptr, cursor (may alias cnt), dinv
__global__ __launch_bounds__(256)
void k_scan3(const int* __restrict__ cnt, const int* __restrict__ boff,
             int* __restrict__ rowptr, int* __restrict__ cursor,
             float* __restrict__ dinv, int n) {
    int i = blockIdx.x * 256 + threadIdx.x;
    int v = (i < n) ? cnt[i] : 0;
    int lane = threadIdx.x & 63, w = threadIdx.x >> 6;
    int inc = v;
#pragma unroll
    for (int off = 1; off < 64; off <<= 1) {
        int x = __shfl_up(inc, off, 64);
        if (lane >= off) inc += x;
    }
    __shared__ int wtot[4];
    if (lane == 63) wtot[w] = inc;
    __syncthreads();
    int wo = boff[blockIdx.x];
    for (int j = 0; j < w; ++j) wo += wtot[j];
    if (i < n) {
        int excl = wo + inc - v;
        rowptr[i] = excl;
        cursor[i] = excl;
        dinv[i] = rsqrtf(1.0f + (float)v);
        if (i == n - 1) rowptr[n] = excl + v;
    }
}

__global__ void k_fill(const int* __restrict__ src, const int* __restrict__ dst,
                       int* __restrict__ cursor, int* __restrict__ csr_src, int ne) {
    int e = blockIdx.x * blockDim.x + threadIdx.x;
    if (e < ne) {
        int pos = atomicAdd(&cursor[dst[e]], 1);
        csr_src[pos] = src[e];
    }
}

// ---------------- counts via binary search on sorted batch ----------------
__global__ __launch_bounds__(128)
void k_counts_bs(const int* __restrict__ batch, float* __restrict__ counts, int n) {
    __shared__ int lb[65];
    int t = threadIdx.x;
    if (t <= 64) {
        int lo = 0, hi = n;
        while (lo < hi) {
            int mid = (lo + hi) >> 1;
            if (batch[mid] < t) lo = mid + 1; else hi = mid;
        }
        lb[t] = lo;
    }
    __syncthreads();
    if (t < 64) counts[t] = (float)(lb[t + 1] - lb[t]);
}

// ---------------- weight transpose + bf16 split: Wt[n][k] = W[k][n] ----------------
__global__ void k_wsplit(const float* __restrict__ W, u16* __restrict__ Whi, u16* __restrict__ Wlo,
                         int K, int N) {
    int idx = blockIdx.x * blockDim.x + threadIdx.x;
    if (idx >= K * N) return;
    int n = idx / K, k = idx - n * K;
    float w = W[(size_t)k * N + n];
    u16 hi = f2bf(w);
    u16 lo = f2bf(w - bf2f(hi));
    Whi[idx] = hi;
    Wlo[idx] = lo;
}

// ---------------- gather aggregation -> bf16 hi/lo ----------------
// agg[d] = dinv[d] * ( sum_{s in in(d)} dinv[s]*h[s] + dinv[d]*h[d] )
template<int C>
__global__ __launch_bounds__(256)
void k_agg_gather(const int* __restrict__ rowptr, const int* __restrict__ csr_src,
                  const float* __restrict__ dinv, const float* __restrict__ h,
                  u16* __restrict__ out_hi, u16* __restrict__ out_lo, int n) {
    constexpr int V = C / 64;   // floats per lane (2 or 4)
    int node = (blockIdx.x * blockDim.x + threadIdx.x) >> 6;
    int lane = threadIdx.x & 63;
    if (node >= n) return;
    int beg = rowptr[node], end = rowptr[node + 1];
    float di = dinv[node];
    float acc[V];
    {
        const float* hw = h + (size_t)node * C + lane * V;
        if constexpr (V == 4) {
            float4 v = *(const float4*)hw;
            acc[0] = v.x * di; acc[1] = v.y * di; acc[2] = v.z * di; acc[3] = v.w * di;
        } else {
            float2 v = *(const float2*)hw;
            acc[0] = v.x * di; acc[1] = v.y * di;
        }
    }
    int j = beg;
    for (; j + 1 < end; j += 2) {
        int s0 = csr_src[j], s1 = csr_src[j + 1];
        float w0 = dinv[s0], w1 = dinv[s1];
        const float* p0 = h + (size_t)s0 * C + lane * V;
        const float* p1 = h + (size_t)s1 * C + lane * V;
        if constexpr (V == 4) {
            float4 v0 = *(const float4*)p0;
            float4 v1 = *(const float4*)p1;
            acc[0] += v0.x * w0 + v1.x * w1;
            acc[1] += v0.y * w0 + v1.y * w1;
            acc[2] += v0.z * w0 + v1.z * w1;
            acc[3] += v0.w * w0 + v1.w * w1;
        } else {
            float2 v0 = *(const float2*)p0;
            float2 v1 = *(const float2*)p1;
            acc[0] += v0.x * w0 + v1.x * w1;
            acc[1] += v0.y * w0 + v1.y * w1;
        }
    }
    if (j < end) {
        int s0 = csr_src[j];
        float w0 = dinv[s0];
        const float* p0 = h + (size_t)s0 * C + lane * V;
        if constexpr (V == 4) {
            float4 v0 = *(const float4*)p0;
            acc[0] += v0.x * w0; acc[1] += v0.y * w0; acc[2] += v0.z * w0; acc[3] += v0.w * w0;
        } else {
            float2 v0 = *(const float2*)p0;
            acc[0] += v0.x * w0; acc[1] += v0.y * w0;
        }
    }
    u16 hi[V], lo[V];
#pragma unroll
    for (int i = 0; i < V; ++i) {
        float a = acc[i] * di;
        hi[i] = f2bf(a);
        lo[i] = f2bf(a - bf2f(hi[i]));
    }
    if constexpr (V == 4) {
        uint2 ph, pl;
        ph.x = (u32)hi[0] | ((u32)hi[1] << 16); ph.y = (u32)hi[2] | ((u32)hi[3] << 16);
        pl.x = (u32)lo[0] | ((u32)lo[1] << 16); pl.y = (u32)lo[2] | ((u32)lo[3] << 16);
        ((uint2*)out_hi)[(size_t)node * 64 + lane] = ph;
        ((uint2*)out_lo)[(size_t)node * 64 + lane] = pl;
    } else {
        ((u32*)out_hi)[(size_t)node * 64 + lane] = (u32)hi[0] | ((u32)hi[1] << 16);
        ((u32*)out_lo)[(size_t)node * 64 + lane] = (u32)lo[0] | ((u32)lo[1] << 16);
    }
}

// ---------------- MFMA GEMM: C = relu(A@W + b), A split-bf16 [M][K], Wt split-bf16 [256][K] ----------------
template<bool POOL>
__global__ __launch_bounds__(256)
void k_gemm_mfma(const u16* __restrict__ Ahi, const u16* __restrict__ Alo,
                 const u16* __restrict__ Bhi, const u16* __restrict__ Blo,
                 const float* __restrict__ bias, float* __restrict__ out,
                 const int* __restrict__ batch, float* __restrict__ pool,
                 int M, int K) {
    __shared__ u16 lds[4][128 * 32];   // Ahi, Alo, Bhi, Blo tiles: [128 rows][32 k] bf16
    const int tid = threadIdx.x, lane = tid & 63, wid = tid >> 6;
    const int bm = blockIdx.y * 128, bn = blockIdx.x * 128;
    const int wr = (wid >> 1) * 64, wc = (wid & 1) * 64;
    const int lr = lane & 15, kg = lane >> 4;
    const int arow = lane >> 2;          // row within 16-row chunk
    const int acol = (lane & 3) * 8;     // bf16 col offset within 32-wide tile

    f32x4 acc[4][4];
#pragma unroll
    for (int i = 0; i < 4; ++i)
#pragma unroll
        for (int j = 0; j < 4; ++j) acc[i][j] = (f32x4){0.f, 0.f, 0.f, 0.f};

    for (int k0 = 0; k0 < K; k0 += 32) {
#pragma unroll
        for (int i = 0; i < 8; ++i) {
            int c = wid * 8 + i;
            int buf = c >> 3, cc = c & 7;
            const u16* gb = (buf == 0) ? Ahi : (buf == 1) ? Alo : (buf == 2) ? Bhi : Blo;
            int row;
            if (buf < 2) { row = bm + cc * 16 + arow; if (row >= M) row = M - 1; }
            else         { row = bn + cc * 16 + arow; }
            const u16* gp = gb + (size_t)row * K + k0 + acol;
            gll16(gp, &lds[buf][cc * 512]);
        }
        __syncthreads();

        s16x8 ahi[4], alo[4];
#pragma unroll
        for (int fm = 0; fm < 4; ++fm) {
            int r = wr + fm * 16 + lr;
            ahi[fm] = *(const s16x8*)&lds[0][r * 32 + kg * 8];
            alo[fm] = *(const s16x8*)&lds[1][r * 32 + kg * 8];
        }
#pragma unroll
        for (int fn = 0; fn < 4; ++fn) {
            int cidx = wc + fn * 16 + lr;
            s16x8 bhi = *(const s16x8*)&lds[2][cidx * 32 + kg * 8];
            s16x8 blo = *(const s16x8*)&lds[3][cidx * 32 + kg * 8];
#pragma unroll
            for (int fm = 0; fm < 4; ++fm) {
                acc[fm][fn] = __builtin_amdgcn_mfma_f32_16x16x32_bf16(ahi[fm], bhi, acc[fm][fn], 0, 0, 0);
                acc[fm][fn] = __builtin_amdgcn_mfma_f32_16x16x32_bf16(ahi[fm], blo, acc[fm][fn], 0, 0, 0);
                acc[fm][fn] = __builtin_amdgcn_mfma_f32_16x16x32_bf16(alo[fm], bhi, acc[fm][fn], 0, 0, 0);
            }
        }
        __syncthreads();
    }

    // epilogue: D row = bm + wr + fm*16 + kg*4 + r ; col = bn + wc + fn*16 + lr
#pragma unroll
    for (int fn = 0; fn < 4; ++fn) {
        int col = bn + wc + fn * 16 + lr;
        float bv = bias[col];
        if (!POOL) {
#pragma unroll
            for (int fm = 0; fm < 4; ++fm) {
                int rbase = bm + wr + fm * 16 + kg * 4;
#pragma unroll
                for (int r = 0; r < 4; ++r) {
                    int row = rbase + r;
                    if (row < M)
                        out[(size_t)row * 256 + col] = fmaxf(acc[fm][fn][r] + bv, 0.f);
                }
            }
        } else {
            int gcur = -1;
            float run = 0.f;
#pragma unroll
            for (int fm = 0; fm < 4; ++fm) {
                int rbase = bm + wr + fm * 16 + kg * 4;
#pragma unroll
                for (int r = 0; r < 4; ++r) {
                    int row = rbase + r;
                    if (row < M) {
                        int g = batch[row];
                        float v = fmaxf(acc[fm][fn][r] + bv, 0.f);
                        if (g != gcur) {
                            if (gcur >= 0) atomicAdd(&pool[gcur * 256 + col], run);
                            gcur = g;
                            run = 0.f;
                        }
                        run += v;
                    }
                }
            }
            if (gcur >= 0) atomicAdd(&pool[gcur * 256 + col], run);
        }
    }
}

// ---------------- pool helpers ----------------
__global__ void k_zero(float* p, int n) {
    int i = blockIdx.x * blockDim.x + threadIdx.x;
    if (i < n) p[i] = 0.0f;
}

// ---------------- dense head ----------------
__global__ __launch_bounds__(128)
void k_dense(const float* __restrict__ sums, const float* __restrict__ counts,
             const float* __restrict__ W3, const float* __restrict__ b3,
             const float* __restrict__ W4, const float* __restrict__ b4,
             float* __restrict__ out) {
    __shared__ float g[256];
    __shared__ float hid[128];
    int gi = blockIdx.x;
    int t = threadIdx.x;
    float inv = 1.0f / fmaxf(counts[gi], 1.0f);
    for (int c = t; c < 256; c += 128) g[c] = sums[gi * 256 + c] * inv;
    __syncthreads();
    float acc = b3[t];
    for (int k = 0; k < 256; ++k) acc += g[k] * W3[k * 128 + t];
    hid[t] = fmaxf(acc, 0.0f);
    __syncthreads();
    if (t < 10) {
        float o = b4[t];
        for (int k = 0; k < 128; ++k) o += hid[k] * W4[k * 10 + t];
        out[gi * 10 + t] = o;
    }
}

extern "C" void kernel_launch(void* const* d_in, const int* in_sizes, int n_in,
                              void* d_out, int out_size, void* d_ws, size_t ws_size,
                              hipStream_t stream) {
    const float* x   = (const float*)d_in[0];
    const int*  eidx = (const int*)d_in[1];    // [2, NE]
    const int*  batch= (const int*)d_in[2];
    const float* W1 = (const float*)d_in[3];
    const float* b1 = (const float*)d_in[4];
    const float* W2 = (const float*)d_in[5];
    const float* b2 = (const float*)d_in[6];
    const float* W3 = (const float*)d_in[7];
    const float* b3 = (const float*)d_in[8];
    const float* W4 = (const float*)d_in[9];
    const float* b4 = (const float*)d_in[10];
    float* out = (float*)d_out;

    const int N = NN, E = NE, G = NG;
    const int* src = eidx;
    const int* dst = eidx + E;
    const int NB = (N + 255) / 256;    // 196 scan blocks (<= 256)

    // workspace layout (256B-aligned slices)
    char* p = (char*)d_ws;
    auto alloc = [&](size_t bytes) { char* r = p; p += (bytes + 255) & ~(size_t)255; return r; };
    float* h1     = (float*)alloc((size_t)N * 256 * 4);
    float* dinv   = (float*)alloc((size_t)N * 4);
    float* sums   = (float*)alloc((size_t)G * 256 * 4);
    float* counts = (float*)alloc((size_t)G * 4);
    int*   cnt    = (int*)alloc((size_t)N * 4);        // reused as cursor after scan
    int*   rowptr = (int*)alloc((size_t)(N + 1) * 4);
    int*   bsum   = (int*)alloc((size_t)NB * 4);
    int*   csr    = (int*)alloc((size_t)E * 4);
    u16*   axhi   = (u16*)alloc((size_t)N * 128 * 2);
    u16*   axlo   = (u16*)alloc((size_t)N * 128 * 2);
    u16*   a2hi   = (u16*)alloc((size_t)N * 256 * 2);
    u16*   a2lo   = (u16*)alloc((size_t)N * 256 * 2);
    u16*   w1hi   = (u16*)alloc((size_t)256 * 128 * 2);
    u16*   w1lo   = (u16*)alloc((size_t)256 * 128 * 2);
    u16*   w2hi   = (u16*)alloc((size_t)256 * 256 * 2);
    u16*   w2lo   = (u16*)alloc((size_t)256 * 256 * 2);
    int*   cursor = cnt;

    // CSR build + dinv
    k_zero_int<<<NB, 256, 0, stream>>>(cnt, N);
    k_hist<<<(E + 255) / 256, 256, 0, stream>>>(dst, cnt, E);
    k_scan1<<<NB, 256, 0, stream>>>(cnt, bsum, N);
    k_scan2<<<1, 256, 0, stream>>>(bsum, NB);
    k_scan3<<<NB, 256, 0, stream>>>(cnt, bsum, rowptr, cursor, dinv, N);
    k_fill<<<(E + 255) / 256, 256, 0, stream>>>(src, dst, cursor, csr, E);

    // counts (sorted batch -> binary search) + zero pool sums
    k_counts_bs<<<1, 128, 0, stream>>>(batch, counts, N);
    k_zero<<<(G * 256 + 255) / 256, 256, 0, stream>>>(sums, G * 256);

    // weight transpose+split
    k_wsplit<<<(128 * 256 + 255) / 256, 256, 0, stream>>>(W1, w1hi, w1lo, 128, 256);
    k_wsplit<<<(256 * 256 + 255) / 256, 256, 0, stream>>>(W2, w2hi, w2lo, 256, 256);

    // conv1: gather-aggregate x (128ch) -> split bf16, then MFMA GEMM K=128 -> h1 (fp32, relu+bias)
    k_agg_gather<128><<<(N + 3) / 4, 256, 0, stream>>>(rowptr, csr, dinv, x, axhi, axlo, N);
    dim3 ggrid(2, (N + 127) / 128);
    k_gemm_mfma<false><<<ggrid, 256, 0, stream>>>(axhi, axlo, w1hi, w1lo, b1, h1,
                                                  nullptr, nullptr, N, 128);

    // conv2: gather-aggregate h1 (256ch) -> split bf16, then MFMA GEMM K=256 fused into pool
    k_agg_gather<256><<<(N + 3) / 4, 256, 0, stream>>>(rowptr, csr, dinv, h1, a2hi, a2lo, N);
    k_gemm_mfma<true><<<ggrid, 256, 0, stream>>>(a2hi, a2lo, w2hi, w2lo, b2, nullptr,
                                                 batch, sums, N, 256);

    // dense head
    k_dense<<<G, 128, 0, stream>>>(sums, counts, W3, b3, W4, b4, out);
}

// Round 5
// 292.718 us; speedup vs baseline: 11.4368x; 1.1721x over previous
//
#include <hip/hip_runtime.h>

typedef unsigned short u16;
typedef unsigned int u32;
typedef __attribute__((ext_vector_type(8))) short s16x8;
typedef __attribute__((ext_vector_type(4))) float f32x4;

#define NN 50000
#define NE 600000
#define NG 64

__device__ __forceinline__ u16 f2bf(float f) {
    u32 u = __float_as_uint(f);
    u32 r = (u + 0x7fffu + ((u >> 16) & 1u)) >> 16;
    return (u16)r;
}
__device__ __forceinline__ float bf2f(u16 h) {
    return __uint_as_float(((u32)h) << 16);
}
__device__ __forceinline__ void gll16(const void* g, void* l) {
    __builtin_amdgcn_global_load_lds((const __attribute__((address_space(1))) u32*)g,
                                     (__attribute__((address_space(3))) u32*)l, 16, 0, 0);
}

// ---------------- CSR build ----------------
__global__ void k_zero_int(int* p, int n) {
    int i = blockIdx.x * blockDim.x + threadIdx.x;
    if (i < n) p[i] = 0;
}

__global__ void k_hist(const int* __restrict__ dst, int* __restrict__ cnt, int ne) {
    int e = blockIdx.x * blockDim.x + threadIdx.x;
    if (e < ne) atomicAdd(&cnt[dst[e]], 1);
}

__global__ __launch_bounds__(256)
void k_scan1(const int* __restrict__ cnt, int* __restrict__ bsum, int n) {
    int i = blockIdx.x * 256 + threadIdx.x;
    int v = (i < n) ? cnt[i] : 0;
#pragma unroll
    for (int off = 32; off > 0; off >>= 1) v += __shfl_down(v, off, 64);
    __shared__ int ws[4];
    int lane = threadIdx.x & 63, w = threadIdx.x >> 6;
    if (lane == 0) ws[w] = v;
    __syncthreads();
    if (threadIdx.x == 0) bsum[blockIdx.x] = ws[0] + ws[1] + ws[2] + ws[3];
}

__global__ __launch_bounds__(256)
void k_scan2(int* __restrict__ bsum, int nb) {
    int t = threadIdx.x;
    int v = (t < nb) ? bsum[t] : 0;
    int lane = t & 63, w = t >> 6;
    int inc = v;
#pragma unroll
    for (int off = 1; off < 64; off <<= 1) {
        int x = __shfl_up(inc, off, 64);
        if (lane >= off) inc += x;
    }
    __shared__ int wtot[4];
    if (lane == 63) wtot[w] = inc;
    __syncthreads();
    int wo = 0;
    for (int j = 0; j < w; ++j) wo += wtot[j];
    if (t < nb) bsum[t] = wo + inc - v;   // exclusive
}

__global__ __launch_bounds__(256)
void k_scan3(const int* __restrict__ cnt, const int* __restrict__ boff,
             int* __restrict__ rowptr, int* __restrict__ cursor,
             float* __restrict__ dinv, int n) {
    int i = blockIdx.x * 256 + threadIdx.x;
    int v = (i < n) ? cnt[i] : 0;
    int lane = threadIdx.x & 63, w = threadIdx.x >> 6;
    int inc = v;
#pragma unroll
    for (int off = 1; off < 64; off <<= 1) {
        int x = __shfl_up(inc, off, 64);
        if (lane >= off) inc += x;
    }
    __shared__ int wtot[4];
    if (lane == 63) wtot[w] = inc;
    __syncthreads();
    int wo = boff[blockIdx.x];
    for (int j = 0; j < w; ++j) wo += wtot[j];
    if (i < n) {
        int excl = wo + inc - v;
        rowptr[i] = excl;
        cursor[i] = excl;
        dinv[i] = rsqrtf(1.0f + (float)v);
        if (i == n - 1) rowptr[n] = excl + v;
    }
}

__global__ void k_fill(const int* __restrict__ src, const int* __restrict__ dst,
                       int* __restrict__ cursor, int* __restrict__ csr_src, int ne) {
    int e = blockIdx.x * blockDim.x + threadIdx.x;
    if (e < ne) {
        int pos = atomicAdd(&cursor[dst[e]], 1);
        csr_src[pos] = src[e];
    }
}

// ---------------- counts via binary search on sorted batch ----------------
__global__ __launch_bounds__(128)
void k_counts_bs(const int* __restrict__ batch, float* __restrict__ counts, int n) {
    __shared__ int lb[65];
    int t = threadIdx.x;
    if (t <= 64) {
        int lo = 0, hi = n;
        while (lo < hi) {
            int mid = (lo + hi) >> 1;
            if (batch[mid] < t) lo = mid + 1; else hi = mid;
        }
        lb[t] = lo;
    }
    __syncthreads();
    if (t < 64) counts[t] = (float)(lb[t + 1] - lb[t]);
}

// ---------------- fp32 -> bf16 (round nearest) elementwise, 4/thread ----------------
__global__ void k_f2bf4(const float* __restrict__ in, u16* __restrict__ out, int n4) {
    int i = blockIdx.x * blockDim.x + threadIdx.x;
    if (i >= n4) return;
    float4 v = ((const float4*)in)[i];
    ushort4 o;
    o.x = f2bf(v.x); o.y = f2bf(v.y); o.z = f2bf(v.z); o.w = f2bf(v.w);
    ((ushort4*)out)[i] = o;
}

// ---------------- weight transpose + bf16 split: Wt[n][k] = W[k][n] ----------------
__global__ void k_wsplit(const float* __restrict__ W, u16* __restrict__ Whi, u16* __restrict__ Wlo,
                         int K, int N) {
    int idx = blockIdx.x * blockDim.x + threadIdx.x;
    if (idx >= K * N) return;
    int n = idx / K, k = idx - n * K;
    float w = W[(size_t)k * N + n];
    u16 hi = f2bf(w);
    u16 lo = f2bf(w - bf2f(hi));
    Whi[idx] = hi;
    Wlo[idx] = lo;
}

// ---------------- gather aggregation from bf16 source -> bf16 hi/lo ----------------
// agg[d] = dinv[d] * ( sum_{s in in(d)} dinv[s]*hb[s] + dinv[d]*hb[d] )
template<int C>   // C=128: u32/lane (2 bf16); C=256: uint2/lane (4 bf16)
__global__ __launch_bounds__(256)
void k_agg_gather(const int* __restrict__ rowptr, const int* __restrict__ csr_src,
                  const float* __restrict__ dinv, const u16* __restrict__ hb,
                  u16* __restrict__ out_hi, u16* __restrict__ out_lo, int n) {
    constexpr int V = C / 64;   // bf16 per lane (2 or 4)
    int node = (blockIdx.x * blockDim.x + threadIdx.x) >> 6;
    int lane = threadIdx.x & 63;
    if (node >= n) return;
    int beg = rowptr[node], end = rowptr[node + 1];
    float di = dinv[node];
    float acc[V];
    if constexpr (V == 4) {
        uint2 v = ((const uint2*)hb)[(size_t)node * 64 + lane];
        acc[0] = bf2f((u16)v.x) * di; acc[1] = bf2f((u16)(v.x >> 16)) * di;
        acc[2] = bf2f((u16)v.y) * di; acc[3] = bf2f((u16)(v.y >> 16)) * di;
    } else {
        u32 v = ((const u32*)hb)[(size_t)node * 64 + lane];
        acc[0] = bf2f((u16)v) * di; acc[1] = bf2f((u16)(v >> 16)) * di;
    }
    int j = beg;
    for (; j + 1 < end; j += 2) {
        int s0 = csr_src[j], s1 = csr_src[j + 1];
        float w0 = dinv[s0], w1 = dinv[s1];
        if constexpr (V == 4) {
            uint2 v0 = ((const uint2*)hb)[(size_t)s0 * 64 + lane];
            uint2 v1 = ((const uint2*)hb)[(size_t)s1 * 64 + lane];
            acc[0] += bf2f((u16)v0.x) * w0 + bf2f((u16)v1.x) * w1;
            acc[1] += bf2f((u16)(v0.x >> 16)) * w0 + bf2f((u16)(v1.x >> 16)) * w1;
            acc[2] += bf2f((u16)v0.y) * w0 + bf2f((u16)v1.y) * w1;
            acc[3] += bf2f((u16)(v0.y >> 16)) * w0 + bf2f((u16)(v1.y >> 16)) * w1;
        } else {
            u32 v0 = ((const u32*)hb)[(size_t)s0 * 64 + lane];
            u32 v1 = ((const u32*)hb)[(size_t)s1 * 64 + lane];
            acc[0] += bf2f((u16)v0) * w0 + bf2f((u16)v1) * w1;
            acc[1] += bf2f((u16)(v0 >> 16)) * w0 + bf2f((u16)(v1 >> 16)) * w1;
        }
    }
    if (j < end) {
        int s0 = csr_src[j];
        float w0 = dinv[s0];
        if constexpr (V == 4) {
            uint2 v0 = ((const uint2*)hb)[(size_t)s0 * 64 + lane];
            acc[0] += bf2f((u16)v0.x) * w0; acc[1] += bf2f((u16)(v0.x >> 16)) * w0;
            acc[2] += bf2f((u16)v0.y) * w0; acc[3] += bf2f((u16)(v0.y >> 16)) * w0;
        } else {
            u32 v0 = ((const u32*)hb)[(size_t)s0 * 64 + lane];
            acc[0] += bf2f((u16)v0) * w0; acc[1] += bf2f((u16)(v0 >> 16)) * w0;
        }
    }
    u16 hi[V], lo[V];
#pragma unroll
    for (int i = 0; i < V; ++i) {
        float a = acc[i] * di;
        hi[i] = f2bf(a);
        lo[i] = f2bf(a - bf2f(hi[i]));
    }
    if constexpr (V == 4) {
        uint2 ph, pl;
        ph.x = (u32)hi[0] | ((u32)hi[1] << 16); ph.y = (u32)hi[2] | ((u32)hi[3] << 16);
        pl.x = (u32)lo[0] | ((u32)lo[1] << 16); pl.y = (u32)lo[2] | ((u32)lo[3] << 16);
        ((uint2*)out_hi)[(size_t)node * 64 + lane] = ph;
        ((uint2*)out_lo)[(size_t)node * 64 + lane] = pl;
    } else {
        ((u32*)out_hi)[(size_t)node * 64 + lane] = (u32)hi[0] | ((u32)hi[1] << 16);
        ((u32*)out_lo)[(size_t)node * 64 + lane] = (u32)lo[0] | ((u32)lo[1] << 16);
    }
}

// ---------------- MFMA GEMM: BM=128, BN=256 (full width), BK=32, 512 thr / 8 waves ----------------
// A split-bf16 [M][K]; B = Wt split-bf16 [256][K].
// POOL=false: out_bf[row*256+col] = bf16(relu(acc+bias))
// POOL=true : atomicAdd run-length into pool[batch[row]*256+col] (fp32)
// LDS layout per buffer: [kg 0..3][rows][8 bf16] -> 16B slots, conflict-free ds_read_b128.
template<bool POOL>
__global__ __launch_bounds__(512)
void k_gemm_mfma(const u16* __restrict__ Ahi, const u16* __restrict__ Alo,
                 const u16* __restrict__ Bhi, const u16* __restrict__ Blo,
                 const float* __restrict__ bias, u16* __restrict__ out_bf,
                 const int* __restrict__ batch, float* __restrict__ pool,
                 int M, int K) {
    __shared__ u16 lds[24576];  // 48KB: Ahi[0], Alo[4096], Bhi[8192], Blo[16384] (u16 idx)
    const int tid = threadIdx.x, lane = tid & 63, wid = tid >> 6;
    const int bm = blockIdx.x * 128;
    const int wr = (wid >> 2) * 64, wc = (wid & 3) * 64;
    const int lr = lane & 15, kg = lane >> 4;

    f32x4 acc[4][4];
#pragma unroll
    for (int i = 0; i < 4; ++i)
#pragma unroll
        for (int j = 0; j < 4; ++j) acc[i][j] = (f32x4){0.f, 0.f, 0.f, 0.f};

    for (int k0 = 0; k0 < K; k0 += 32) {
        // stage 48 chunks of 1KB; wave w stages chunks w, w+8, ..., w+40
#pragma unroll
        for (int i = 0; i < 6; ++i) {
            int c = wid + 8 * i;
            const u16* gp;
            u32 lbase;
            if (c < 16) {           // A tiles: 8 chunks each
                int cc = c & 7;
                int s = cc * 64 + lane;          // slot 0..511
                int kga = s >> 7, row = s & 127;
                int rg = bm + row; if (rg >= M) rg = M - 1;
                gp = ((c < 8) ? Ahi : Alo) + (size_t)rg * K + k0 + kga * 8;
                lbase = ((c < 8) ? 0 : 4096) + cc * 512;
            } else {                // B tiles: 16 chunks each
                int cc = (c - 16) & 15;
                int s = cc * 64 + lane;          // slot 0..1023
                int kgb = s >> 8, col = s & 255;
                gp = ((c < 32) ? Bhi : Blo) + (size_t)col * K + k0 + kgb * 8;
                lbase = ((c < 32) ? 8192 : 16384) + cc * 512;
            }
            gll16(gp, &lds[lbase]);
        }
        __syncthreads();

        s16x8 ahi[4], alo[4];
#pragma unroll
        for (int fm = 0; fm < 4; ++fm) {
            int row = wr + fm * 16 + lr;
            u32 sa = (u32)(kg * 128 + row) * 8;
            ahi[fm] = *(const s16x8*)&lds[sa];
            alo[fm] = *(const s16x8*)&lds[4096 + sa];
        }
#pragma unroll
        for (int fn = 0; fn < 4; ++fn) {
            int col = wc + fn * 16 + lr;
            u32 sb = (u32)(kg * 256 + col) * 8;
            s16x8 bhi = *(const s16x8*)&lds[8192 + sb];
            s16x8 blo = *(const s16x8*)&lds[16384 + sb];
#pragma unroll
            for (int fm = 0; fm < 4; ++fm) {
                acc[fm][fn] = __builtin_amdgcn_mfma_f32_16x16x32_bf16(ahi[fm], bhi, acc[fm][fn], 0, 0, 0);
                acc[fm][fn] = __builtin_amdgcn_mfma_f32_16x16x32_bf16(ahi[fm], blo, acc[fm][fn], 0, 0, 0);
                acc[fm][fn] = __builtin_amdgcn_mfma_f32_16x16x32_bf16(alo[fm], bhi, acc[fm][fn], 0, 0, 0);
            }
        }
        __syncthreads();
    }

    // epilogue: row = bm + wr + fm*16 + kg*4 + r ; col = wc + fn*16 + lr
#pragma unroll
    for (int fn = 0; fn < 4; ++fn) {
        int col = wc + fn * 16 + lr;
        float bv = bias[col];
        if (!POOL) {
#pragma unroll
            for (int fm = 0; fm < 4; ++fm) {
                int rbase = bm + wr + fm * 16 + kg * 4;
#pragma unroll
                for (int r = 0; r < 4; ++r) {
                    int row = rbase + r;
                    if (row < M)
                        out_bf[(size_t)row * 256 + col] = f2bf(fmaxf(acc[fm][fn][r] + bv, 0.f));
                }
            }
        } else {
            int gcur = -1;
            float run = 0.f;
#pragma unroll
            for (int fm = 0; fm < 4; ++fm) {
                int rbase = bm + wr + fm * 16 + kg * 4;
#pragma unroll
                for (int r = 0; r < 4; ++r) {
                    int row = rbase + r;
                    if (row < M) {
                        int g = batch[row];
                        float v = fmaxf(acc[fm][fn][r] + bv, 0.f);
                        if (g != gcur) {
                            if (gcur >= 0) atomicAdd(&pool[gcur * 256 + col], run);
                            gcur = g;
                            run = 0.f;
                        }
                        run += v;
                    }
                }
            }
            if (gcur >= 0) atomicAdd(&pool[gcur * 256 + col], run);
        }
    }
}

// ---------------- pool helpers ----------------
__global__ void k_zero(float* p, int n) {
    int i = blockIdx.x * blockDim.x + threadIdx.x;
    if (i < n) p[i] = 0.0f;
}

// ---------------- dense head ----------------
__global__ __launch_bounds__(128)
void k_dense(const float* __restrict__ sums, const float* __restrict__ counts,
             const float* __restrict__ W3, const float* __restrict__ b3,
             const float* __restrict__ W4, const float* __restrict__ b4,
             float* __restrict__ out) {
    __shared__ float g[256];
    __shared__ float hid[128];
    int gi = blockIdx.x;
    int t = threadIdx.x;
    float inv = 1.0f / fmaxf(counts[gi], 1.0f);
    for (int c = t; c < 256; c += 128) g[c] = sums[gi * 256 + c] * inv;
    __syncthreads();
    float acc = b3[t];
    for (int k = 0; k < 256; ++k) acc += g[k] * W3[k * 128 + t];
    hid[t] = fmaxf(acc, 0.0f);
    __syncthreads();
    if (t < 10) {
        float o = b4[t];
        for (int k = 0; k < 128; ++k) o += hid[k] * W4[k * 10 + t];
        out[gi * 10 + t] = o;
    }
}

extern "C" void kernel_launch(void* const* d_in, const int* in_sizes, int n_in,
                              void* d_out, int out_size, void* d_ws, size_t ws_size,
                              hipStream_t stream) {
    const float* x   = (const float*)d_in[0];
    const int*  eidx = (const int*)d_in[1];    // [2, NE]
    const int*  batch= (const int*)d_in[2];
    const float* W1 = (const float*)d_in[3];
    const float* b1 = (const float*)d_in[4];
    const float* W2 = (const float*)d_in[5];
    const float* b2 = (const float*)d_in[6];
    const float* W3 = (const float*)d_in[7];
    const float* b3 = (const float*)d_in[8];
    const float* W4 = (const float*)d_in[9];
    const float* b4 = (const float*)d_in[10];
    float* out = (float*)d_out;

    const int N = NN, E = NE, G = NG;
    const int* src = eidx;
    const int* dst = eidx + E;
    const int NB = (N + 255) / 256;

    // workspace layout (256B-aligned slices)
    char* p = (char*)d_ws;
    auto alloc = [&](size_t bytes) { char* r = p; p += (bytes + 255) & ~(size_t)255; return r; };
    u16*   h1bf   = (u16*)alloc((size_t)N * 256 * 2);   // bf16 h1 (gather source for conv2)
    u16*   xbf    = (u16*)alloc((size_t)N * 128 * 2);   // bf16 x  (gather source for conv1)
    float* dinv   = (float*)alloc((size_t)N * 4);
    float* sums   = (float*)alloc((size_t)G * 256 * 4);
    float* counts = (float*)alloc((size_t)G * 4);
    int*   cnt    = (int*)alloc((size_t)N * 4);         // reused as cursor after scan
    int*   rowptr = (int*)alloc((size_t)(N + 1) * 4);
    int*   bsum   = (int*)alloc((size_t)NB * 4);
    int*   csr    = (int*)alloc((size_t)E * 4);
    u16*   axhi   = (u16*)alloc((size_t)N * 128 * 2);
    u16*   axlo   = (u16*)alloc((size_t)N * 128 * 2);
    u16*   a2hi   = (u16*)alloc((size_t)N * 256 * 2);
    u16*   a2lo   = (u16*)alloc((size_t)N * 256 * 2);
    u16*   w1hi   = (u16*)alloc((size_t)256 * 128 * 2);
    u16*   w1lo   = (u16*)alloc((size_t)256 * 128 * 2);
    u16*   w2hi   = (u16*)alloc((size_t)256 * 256 * 2);
    u16*   w2lo   = (u16*)alloc((size_t)256 * 256 * 2);
    int*   cursor = cnt;

    // CSR build + dinv
    k_zero_int<<<NB, 256, 0, stream>>>(cnt, N);
    k_hist<<<(E + 255) / 256, 256, 0, stream>>>(dst, cnt, E);
    k_scan1<<<NB, 256, 0, stream>>>(cnt, bsum, N);
    k_scan2<<<1, 256, 0, stream>>>(bsum, NB);
    k_scan3<<<NB, 256, 0, stream>>>(cnt, bsum, rowptr, cursor, dinv, N);
    k_fill<<<(E + 255) / 256, 256, 0, stream>>>(src, dst, cursor, csr, E);

    // counts + zero pool sums
    k_counts_bs<<<1, 128, 0, stream>>>(batch, counts, N);
    k_zero<<<(G * 256 + 255) / 256, 256, 0, stream>>>(sums, G * 256);

    // weight transpose+split; x -> bf16
    k_wsplit<<<(128 * 256 + 255) / 256, 256, 0, stream>>>(W1, w1hi, w1lo, 128, 256);
    k_wsplit<<<(256 * 256 + 255) / 256, 256, 0, stream>>>(W2, w2hi, w2lo, 256, 256);
    k_f2bf4<<<(N * 32 + 255) / 256, 256, 0, stream>>>(x, xbf, N * 32);

    // conv1: gather-aggregate xbf (128ch) -> split bf16, MFMA GEMM K=128 -> h1bf (bf16, relu+bias)
    k_agg_gather<128><<<(N + 3) / 4, 256, 0, stream>>>(rowptr, csr, dinv, xbf, axhi, axlo, N);
    int gblocks = (N + 127) / 128;
    k_gemm_mfma<false><<<gblocks, 512, 0, stream>>>(axhi, axlo, w1hi, w1lo, b1, h1bf,
                                                    nullptr, nullptr, N, 128);

    // conv2: gather-aggregate h1bf (256ch) -> split bf16, MFMA GEMM K=256 fused into pool
    k_agg_gather<256><<<(N + 3) / 4, 256, 0, stream>>>(rowptr, csr, dinv, h1bf, a2hi, a2lo, N);
    k_gemm_mfma<true><<<gblocks, 512, 0, stream>>>(a2hi, a2lo, w2hi, w2lo, b2, nullptr,
                                                   batch, sums, N, 256);

    // dense head
    k_dense<<<G, 128, 0, stream>>>(sums, counts, W3, b3, W4, b4, out);
}

// Round 6
// 276.157 us; speedup vs baseline: 12.1226x; 1.0600x over previous
//
#include <hip/hip_runtime.h>

typedef unsigned short u16;
typedef unsigned int u32;
typedef __attribute__((ext_vector_type(8))) short s16x8;
typedef __attribute__((ext_vector_type(4))) float f32x4;

#define NN 50000
#define NE 600000
#define NG 64

__device__ __forceinline__ u16 f2bf(float f) {
    u32 u = __float_as_uint(f);
    u32 r = (u + 0x7fffu + ((u >> 16) & 1u)) >> 16;
    return (u16)r;
}
__device__ __forceinline__ float bf2f(u16 h) {
    return __uint_as_float(((u32)h) << 16);
}
__device__ __forceinline__ void gll16(const void* g, void* l) {
    __builtin_amdgcn_global_load_lds((const __attribute__((address_space(1))) u32*)g,
                                     (__attribute__((address_space(3))) u32*)l, 16, 0, 0);
}

// ---------------- CSR build ----------------
__global__ void k_zero_int(int* p, int n) {
    int i = blockIdx.x * blockDim.x + threadIdx.x;
    if (i < n) p[i] = 0;
}

__global__ void k_hist(const int* __restrict__ dst, int* __restrict__ cnt, int ne) {
    int e = blockIdx.x * blockDim.x + threadIdx.x;
    if (e < ne) atomicAdd(&cnt[dst[e]], 1);
}

__global__ __launch_bounds__(256)
void k_scan1(const int* __restrict__ cnt, int* __restrict__ bsum, int n) {
    int i = blockIdx.x * 256 + threadIdx.x;
    int v = (i < n) ? cnt[i] : 0;
#pragma unroll
    for (int off = 32; off > 0; off >>= 1) v += __shfl_down(v, off, 64);
    __shared__ int ws[4];
    int lane = threadIdx.x & 63, w = threadIdx.x >> 6;
    if (lane == 0) ws[w] = v;
    __syncthreads();
    if (threadIdx.x == 0) bsum[blockIdx.x] = ws[0] + ws[1] + ws[2] + ws[3];
}

__global__ __launch_bounds__(256)
void k_scan2(int* __restrict__ bsum, int nb) {
    int t = threadIdx.x;
    int v = (t < nb) ? bsum[t] : 0;
    int lane = t & 63, w = t >> 6;
    int inc = v;
#pragma unroll
    for (int off = 1; off < 64; off <<= 1) {
        int x = __shfl_up(inc, off, 64);
        if (lane >= off) inc += x;
    }
    __shared__ int wtot[4];
    if (lane == 63) wtot[w] = inc;
    __syncthreads();
    int wo = 0;
    for (int j = 0; j < w; ++j) wo += wtot[j];
    if (t < nb) bsum[t] = wo + inc - v;   // exclusive
}

__global__ __launch_bounds__(256)
void k_scan3(const int* __restrict__ cnt, const int* __restrict__ boff,
             int* __restrict__ rowptr, int* __restrict__ cursor,
             float* __restrict__ dinv, int n) {
    int i = blockIdx.x * 256 + threadIdx.x;
    int v = (i < n) ? cnt[i] : 0;
    int lane = threadIdx.x & 63, w = threadIdx.x >> 6;
    int inc = v;
#pragma unroll
    for (int off = 1; off < 64; off <<= 1) {
        int x = __shfl_up(inc, off, 64);
        if (lane >= off) inc += x;
    }
    __shared__ int wtot[4];
    if (lane == 63) wtot[w] = inc;
    __syncthreads();
    int wo = boff[blockIdx.x];
    for (int j = 0; j < w; ++j) wo += wtot[j];
    if (i < n) {
        int excl = wo + inc - v;
        rowptr[i] = excl;
        cursor[i] = excl;
        dinv[i] = rsqrtf(1.0f + (float)v);
        if (i == n - 1) rowptr[n] = excl + v;
    }
}

__global__ void k_fill(const int* __restrict__ src, const int* __restrict__ dst,
                       int* __restrict__ cursor, int* __restrict__ csr_src, int ne) {
    int e = blockIdx.x * blockDim.x + threadIdx.x;
    if (e < ne) {
        int pos = atomicAdd(&cursor[dst[e]], 1);
        csr_src[pos] = src[e];
    }
}

// ---------------- counts via binary search on sorted batch ----------------
__global__ __launch_bounds__(128)
void k_counts_bs(const int* __restrict__ batch, float* __restrict__ counts, int n) {
    __shared__ int lb[65];
    int t = threadIdx.x;
    if (t <= 64) {
        int lo = 0, hi = n;
        while (lo < hi) {
            int mid = (lo + hi) >> 1;
            if (batch[mid] < t) lo = mid + 1; else hi = mid;
        }
        lb[t] = lo;
    }
    __syncthreads();
    if (t < 64) counts[t] = (float)(lb[t + 1] - lb[t]);
}

// ---------------- fp32 -> bf16 elementwise, 4/thread ----------------
__global__ void k_f2bf4(const float* __restrict__ in, u16* __restrict__ out, int n4) {
    int i = blockIdx.x * blockDim.x + threadIdx.x;
    if (i >= n4) return;
    float4 v = ((const float4*)in)[i];
    ushort4 o;
    o.x = f2bf(v.x); o.y = f2bf(v.y); o.z = f2bf(v.z); o.w = f2bf(v.w);
    ((ushort4*)out)[i] = o;
}

// ---------------- weight transpose + bf16 split: Wt[n][k] = W[k][n] ----------------
__global__ void k_wsplit(const float* __restrict__ W, u16* __restrict__ Whi, u16* __restrict__ Wlo,
                         int K, int N) {
    int idx = blockIdx.x * blockDim.x + threadIdx.x;
    if (idx >= K * N) return;
    int n = idx / K, k = idx - n * K;
    float w = W[(size_t)k * N + n];
    u16 hi = f2bf(w);
    u16 lo = f2bf(w - bf2f(hi));
    Whi[idx] = hi;
    Wlo[idx] = lo;
}

// ---------------- gather aggregation from bf16 source -> single bf16 out ----------------
// agg[d] = dinv[d] * ( sum_{s in in(d)} dinv[s]*hb[s] + dinv[d]*hb[d] )
template<int C>   // C=128: u32/lane (2 bf16); C=256: uint2/lane (4 bf16)
__global__ __launch_bounds__(256)
void k_agg_gather(const int* __restrict__ rowptr, const int* __restrict__ csr_src,
                  const float* __restrict__ dinv, const u16* __restrict__ hb,
                  u16* __restrict__ out, int n) {
    constexpr int V = C / 64;   // bf16 per lane (2 or 4)
    int node = (blockIdx.x * blockDim.x + threadIdx.x) >> 6;
    int lane = threadIdx.x & 63;
    if (node >= n) return;
    int beg = rowptr[node], end = rowptr[node + 1];
    float di = dinv[node];
    float acc[V];
    if constexpr (V == 4) {
        uint2 v = ((const uint2*)hb)[(size_t)node * 64 + lane];
        acc[0] = bf2f((u16)v.x) * di; acc[1] = bf2f((u16)(v.x >> 16)) * di;
        acc[2] = bf2f((u16)v.y) * di; acc[3] = bf2f((u16)(v.y >> 16)) * di;
    } else {
        u32 v = ((const u32*)hb)[(size_t)node * 64 + lane];
        acc[0] = bf2f((u16)v) * di; acc[1] = bf2f((u16)(v >> 16)) * di;
    }
    int j = beg;
    for (; j + 1 < end; j += 2) {
        int s0 = csr_src[j], s1 = csr_src[j + 1];
        float w0 = dinv[s0], w1 = dinv[s1];
        if constexpr (V == 4) {
            uint2 v0 = ((const uint2*)hb)[(size_t)s0 * 64 + lane];
            uint2 v1 = ((const uint2*)hb)[(size_t)s1 * 64 + lane];
            acc[0] += bf2f((u16)v0.x) * w0 + bf2f((u16)v1.x) * w1;
            acc[1] += bf2f((u16)(v0.x >> 16)) * w0 + bf2f((u16)(v1.x >> 16)) * w1;
            acc[2] += bf2f((u16)v0.y) * w0 + bf2f((u16)v1.y) * w1;
            acc[3] += bf2f((u16)(v0.y >> 16)) * w0 + bf2f((u16)(v1.y >> 16)) * w1;
        } else {
            u32 v0 = ((const u32*)hb)[(size_t)s0 * 64 + lane];
            u32 v1 = ((const u32*)hb)[(size_t)s1 * 64 + lane];
            acc[0] += bf2f((u16)v0) * w0 + bf2f((u16)v1) * w1;
            acc[1] += bf2f((u16)(v0 >> 16)) * w0 + bf2f((u16)(v1 >> 16)) * w1;
        }
    }
    if (j < end) {
        int s0 = csr_src[j];
        float w0 = dinv[s0];
        if constexpr (V == 4) {
            uint2 v0 = ((const uint2*)hb)[(size_t)s0 * 64 + lane];
            acc[0] += bf2f((u16)v0.x) * w0; acc[1] += bf2f((u16)(v0.x >> 16)) * w0;
            acc[2] += bf2f((u16)v0.y) * w0; acc[3] += bf2f((u16)(v0.y >> 16)) * w0;
        } else {
            u32 v0 = ((const u32*)hb)[(size_t)s0 * 64 + lane];
            acc[0] += bf2f((u16)v0) * w0; acc[1] += bf2f((u16)(v0 >> 16)) * w0;
        }
    }
    if constexpr (V == 4) {
        uint2 o;
        o.x = (u32)f2bf(acc[0] * di) | ((u32)f2bf(acc[1] * di) << 16);
        o.y = (u32)f2bf(acc[2] * di) | ((u32)f2bf(acc[3] * di) << 16);
        ((uint2*)out)[(size_t)node * 64 + lane] = o;
    } else {
        ((u32*)out)[(size_t)node * 64 + lane] =
            (u32)f2bf(acc[0] * di) | ((u32)f2bf(acc[1] * di) << 16);
    }
}

// ---------------- MFMA GEMM: BM=128, BN=256, BK=32, 512 thr / 8 waves ----------------
// A single-bf16 [M][K]; B = Wt split-bf16 [256][K]. 2 products: A*Bhi + A*Blo.
// Double-buffered LDS (2 x 40KB), stage-early: next tile's global_load_lds issued
// before current tile's ds_read+MFMA; single barrier per K-step.
// LDS per buf (u16 idx): A[0,4096) Bhi[4096,12288) Blo[12288,20480); chunk layout
// [kg][row|col][8] -> 16B slots, conflict-free ds_read_b128, linear gll16 dests.
__device__ __forceinline__ void stage_tile(u16* ldsbuf, const u16* A, const u16* Bhi,
                                           const u16* Blo, int bm, int k0, int M, int K,
                                           int wid, int lane) {
#pragma unroll
    for (int i = 0; i < 5; ++i) {
        int c = wid + 8 * i;                 // 40 chunks of 1KB
        const u16* gp;
        u32 lbase;
        if (c < 8) {                         // A: 8 chunks
            int s = c * 64 + lane;           // slot 0..511
            int kga = s >> 7, row = s & 127;
            int rg = bm + row; if (rg >= M) rg = M - 1;
            gp = A + (size_t)rg * K + k0 + kga * 8;
            lbase = c * 512;
        } else if (c < 24) {                 // Bhi: 16 chunks
            int cc = c - 8;
            int s = cc * 64 + lane;          // slot 0..1023
            int kgb = s >> 8, col = s & 255;
            gp = Bhi + (size_t)col * K + k0 + kgb * 8;
            lbase = 4096 + cc * 512;
        } else {                             // Blo: 16 chunks
            int cc = c - 24;
            int s = cc * 64 + lane;
            int kgb = s >> 8, col = s & 255;
            gp = Blo + (size_t)col * K + k0 + kgb * 8;
            lbase = 12288 + cc * 512;
        }
        gll16(gp, ldsbuf + lbase);
    }
}

template<bool POOL>
__global__ __launch_bounds__(512)
void k_gemm_mfma(const u16* __restrict__ A, const u16* __restrict__ Bhi,
                 const u16* __restrict__ Blo,
                 const float* __restrict__ bias, u16* __restrict__ out_bf,
                 const int* __restrict__ batch, float* __restrict__ pool,
                 int M, int K) {
    __shared__ u16 lds[2][20480];   // 80KB total
    const int tid = threadIdx.x, lane = tid & 63, wid = tid >> 6;
    const int bm = blockIdx.x * 128;
    const int wr = (wid >> 2) * 64, wc = (wid & 3) * 64;
    const int lr = lane & 15, kg = lane >> 4;

    f32x4 acc[4][4];
#pragma unroll
    for (int i = 0; i < 4; ++i)
#pragma unroll
        for (int j = 0; j < 4; ++j) acc[i][j] = (f32x4){0.f, 0.f, 0.f, 0.f};

    const int nt = K >> 5;
    stage_tile(lds[0], A, Bhi, Blo, bm, 0, M, K, wid, lane);
    __syncthreads();

    for (int t = 0; t < nt; ++t) {
        int cur = t & 1;
        if (t + 1 < nt)
            stage_tile(lds[cur ^ 1], A, Bhi, Blo, bm, (t + 1) << 5, M, K, wid, lane);
        const u16* lb = lds[cur];
        s16x8 a[4];
#pragma unroll
        for (int fm = 0; fm < 4; ++fm)
            a[fm] = *(const s16x8*)&lb[(u32)(kg * 128 + wr + fm * 16 + lr) * 8];
#pragma unroll
        for (int fn = 0; fn < 4; ++fn) {
            int col = wc + fn * 16 + lr;
            u32 sb = (u32)(kg * 256 + col) * 8;
            s16x8 bhi = *(const s16x8*)&lb[4096 + sb];
            s16x8 blo = *(const s16x8*)&lb[12288 + sb];
#pragma unroll
            for (int fm = 0; fm < 4; ++fm) {
                acc[fm][fn] = __builtin_amdgcn_mfma_f32_16x16x32_bf16(a[fm], bhi, acc[fm][fn], 0, 0, 0);
                acc[fm][fn] = __builtin_amdgcn_mfma_f32_16x16x32_bf16(a[fm], blo, acc[fm][fn], 0, 0, 0);
            }
        }
        __syncthreads();   // drains vmem (stage) + lds reads; one barrier per K-step
    }

    // epilogue: row = bm + wr + fm*16 + kg*4 + r ; col = wc + fn*16 + lr
#pragma unroll
    for (int fn = 0; fn < 4; ++fn) {
        int col = wc + fn * 16 + lr;
        float bv = bias[col];
        if (!POOL) {
#pragma unroll
            for (int fm = 0; fm < 4; ++fm) {
                int rbase = bm + wr + fm * 16 + kg * 4;
#pragma unroll
                for (int r = 0; r < 4; ++r) {
                    int row = rbase + r;
                    if (row < M)
                        out_bf[(size_t)row * 256 + col] = f2bf(fmaxf(acc[fm][fn][r] + bv, 0.f));
                }
            }
        } else {
            int gcur = -1;
            float run = 0.f;
#pragma unroll
            for (int fm = 0; fm < 4; ++fm) {
                int rbase = bm + wr + fm * 16 + kg * 4;
#pragma unroll
                for (int r = 0; r < 4; ++r) {
                    int row = rbase + r;
                    if (row < M) {
                        int g = batch[row];
                        float v = fmaxf(acc[fm][fn][r] + bv, 0.f);
                        if (g != gcur) {
                            if (gcur >= 0) atomicAdd(&pool[gcur * 256 + col], run);
                            gcur = g;
                            run = 0.f;
                        }
                        run += v;
                    }
                }
            }
            if (gcur >= 0) atomicAdd(&pool[gcur * 256 + col], run);
        }
    }
}

// ---------------- pool helpers ----------------
__global__ void k_zero(float* p, int n) {
    int i = blockIdx.x * blockDim.x + threadIdx.x;
    if (i < n) p[i] = 0.0f;
}

// ---------------- dense head ----------------
__global__ __launch_bounds__(128)
void k_dense(const float* __restrict__ sums, const float* __restrict__ counts,
             const float* __restrict__ W3, const float* __restrict__ b3,
             const float* __restrict__ W4, const float* __restrict__ b4,
             float* __restrict__ out) {
    __shared__ float g[256];
    __shared__ float hid[128];
    int gi = blockIdx.x;
    int t = threadIdx.x;
    float inv = 1.0f / fmaxf(counts[gi], 1.0f);
    for (int c = t; c < 256; c += 128) g[c] = sums[gi * 256 + c] * inv;
    __syncthreads();
    float acc = b3[t];
    for (int k = 0; k < 256; ++k) acc += g[k] * W3[k * 128 + t];
    hid[t] = fmaxf(acc, 0.0f);
    __syncthreads();
    if (t < 10) {
        float o = b4[t];
        for (int k = 0; k < 128; ++k) o += hid[k] * W4[k * 10 + t];
        out[gi * 10 + t] = o;
    }
}

extern "C" void kernel_launch(void* const* d_in, const int* in_sizes, int n_in,
                              void* d_out, int out_size, void* d_ws, size_t ws_size,
                              hipStream_t stream) {
    const float* x   = (const float*)d_in[0];
    const int*  eidx = (const int*)d_in[1];    // [2, NE]
    const int*  batch= (const int*)d_in[2];
    const float* W1 = (const float*)d_in[3];
    const float* b1 = (const float*)d_in[4];
    const float* W2 = (const float*)d_in[5];
    const float* b2 = (const float*)d_in[6];
    const float* W3 = (const float*)d_in[7];
    const float* b3 = (const float*)d_in[8];
    const float* W4 = (const float*)d_in[9];
    const float* b4 = (const float*)d_in[10];
    float* out = (float*)d_out;

    const int N = NN, E = NE, G = NG;
    const int* src = eidx;
    const int* dst = eidx + E;
    const int NB = (N + 255) / 256;

    // workspace layout (256B-aligned slices)
    char* p = (char*)d_ws;
    auto alloc = [&](size_t bytes) { char* r = p; p += (bytes + 255) & ~(size_t)255; return r; };
    u16*   h1bf   = (u16*)alloc((size_t)N * 256 * 2);   // bf16 h1 (gather source for conv2)
    u16*   xbf    = (u16*)alloc((size_t)N * 128 * 2);   // bf16 x  (gather source for conv1)
    float* dinv   = (float*)alloc((size_t)N * 4);
    float* sums   = (float*)alloc((size_t)G * 256 * 4);
    float* counts = (float*)alloc((size_t)G * 4);
    int*   cnt    = (int*)alloc((size_t)N * 4);         // reused as cursor after scan
    int*   rowptr = (int*)alloc((size_t)(N + 1) * 4);
    int*   bsum   = (int*)alloc((size_t)NB * 4);
    int*   csr    = (int*)alloc((size_t)E * 4);
    u16*   agg1   = (u16*)alloc((size_t)N * 128 * 2);   // bf16 aggregated x (GEMM1 A)
    u16*   agg2   = (u16*)alloc((size_t)N * 256 * 2);   // bf16 aggregated h1 (GEMM2 A)
    u16*   w1hi   = (u16*)alloc((size_t)256 * 128 * 2);
    u16*   w1lo   = (u16*)alloc((size_t)256 * 128 * 2);
    u16*   w2hi   = (u16*)alloc((size_t)256 * 256 * 2);
    u16*   w2lo   = (u16*)alloc((size_t)256 * 256 * 2);
    int*   cursor = cnt;

    // CSR build + dinv
    k_zero_int<<<NB, 256, 0, stream>>>(cnt, N);
    k_hist<<<(E + 255) / 256, 256, 0, stream>>>(dst, cnt, E);
    k_scan1<<<NB, 256, 0, stream>>>(cnt, bsum, N);
    k_scan2<<<1, 256, 0, stream>>>(bsum, NB);
    k_scan3<<<NB, 256, 0, stream>>>(cnt, bsum, rowptr, cursor, dinv, N);
    k_fill<<<(E + 255) / 256, 256, 0, stream>>>(src, dst, cursor, csr, E);

    // counts + zero pool sums
    k_counts_bs<<<1, 128, 0, stream>>>(batch, counts, N);
    k_zero<<<(G * 256 + 255) / 256, 256, 0, stream>>>(sums, G * 256);

    // weight transpose+split; x -> bf16
    k_wsplit<<<(128 * 256 + 255) / 256, 256, 0, stream>>>(W1, w1hi, w1lo, 128, 256);
    k_wsplit<<<(256 * 256 + 255) / 256, 256, 0, stream>>>(W2, w2hi, w2lo, 256, 256);
    k_f2bf4<<<(N * 32 + 255) / 256, 256, 0, stream>>>(x, xbf, N * 32);

    // conv1: gather-aggregate xbf (128ch) -> bf16 A, MFMA GEMM K=128 -> h1bf (relu+bias)
    k_agg_gather<128><<<(N + 3) / 4, 256, 0, stream>>>(rowptr, csr, dinv, xbf, agg1, N);
    int gblocks = (N + 127) / 128;
    k_gemm_mfma<false><<<gblocks, 512, 0, stream>>>(agg1, w1hi, w1lo, b1, h1bf,
                                                    nullptr, nullptr, N, 128);

    // conv2: gather-aggregate h1bf (256ch) -> bf16 A, MFMA GEMM K=256 fused into pool
    k_agg_gather<256><<<(N + 3) / 4, 256, 0, stream>>>(rowptr, csr, dinv, h1bf, agg2, N);
    k_gemm_mfma<true><<<gblocks, 512, 0, stream>>>(agg2, w2hi, w2lo, b2, nullptr,
                                                   batch, sums, N, 256);

    // dense head
    k_dense<<<G, 128, 0, stream>>>(sums, counts, W3, b3, W4, b4, out);
}

// Round 7
// 241.917 us; speedup vs baseline: 13.8384x; 1.1415x over previous
//
#include <hip/hip_runtime.h>

typedef unsigned short u16;
typedef unsigned int u32;
typedef __attribute__((ext_vector_type(8))) short s16x8;
typedef __attribute__((ext_vector_type(4))) float f32x4;

#define NN 50000
#define NE 600000
#define NG 64

__device__ __forceinline__ u16 f2bf(float f) {
    u32 u = __float_as_uint(f);
    u32 r = (u + 0x7fffu + ((u >> 16) & 1u)) >> 16;
    return (u16)r;
}
__device__ __forceinline__ float bf2f(u16 h) {
    return __uint_as_float(((u32)h) << 16);
}
__device__ __forceinline__ void gll16(const void* g, void* l) {
    __builtin_amdgcn_global_load_lds((const __attribute__((address_space(1))) u32*)g,
                                     (__attribute__((address_space(3))) u32*)l, 16, 0, 0);
}

// ---------------- CSR build ----------------
__global__ void k_hist(const int* __restrict__ dst, int* __restrict__ cnt, int ne) {
    int e = blockIdx.x * blockDim.x + threadIdx.x;
    if (e < ne) atomicAdd(&cnt[dst[e]], 1);
}

__global__ __launch_bounds__(256)
void k_scan1(const int* __restrict__ cnt, int* __restrict__ bsum, int n) {
    int i = blockIdx.x * 256 + threadIdx.x;
    int v = (i < n) ? cnt[i] : 0;
#pragma unroll
    for (int off = 32; off > 0; off >>= 1) v += __shfl_down(v, off, 64);
    __shared__ int ws[4];
    int lane = threadIdx.x & 63, w = threadIdx.x >> 6;
    if (lane == 0) ws[w] = v;
    __syncthreads();
    if (threadIdx.x == 0) bsum[blockIdx.x] = ws[0] + ws[1] + ws[2] + ws[3];
}

__global__ __launch_bounds__(256)
void k_scan2(int* __restrict__ bsum, int nb) {
    int t = threadIdx.x;
    int v = (t < nb) ? bsum[t] : 0;
    int lane = t & 63, w = t >> 6;
    int inc = v;
#pragma unroll
    for (int off = 1; off < 64; off <<= 1) {
        int x = __shfl_up(inc, off, 64);
        if (lane >= off) inc += x;
    }
    __shared__ int wtot[4];
    if (lane == 63) wtot[w] = inc;
    __syncthreads();
    int wo = 0;
    for (int j = 0; j < w; ++j) wo += wtot[j];
    if (t < nb) bsum[t] = wo + inc - v;   // exclusive
}

__global__ __launch_bounds__(256)
void k_scan3(const int* __restrict__ cnt, const int* __restrict__ boff,
             int* __restrict__ rowptr, int* __restrict__ cursor,
             float* __restrict__ dinv, int n) {
    int i = blockIdx.x * 256 + threadIdx.x;
    int v = (i < n) ? cnt[i] : 0;
    int lane = threadIdx.x & 63, w = threadIdx.x >> 6;
    int inc = v;
#pragma unroll
    for (int off = 1; off < 64; off <<= 1) {
        int x = __shfl_up(inc, off, 64);
        if (lane >= off) inc += x;
    }
    __shared__ int wtot[4];
    if (lane == 63) wtot[w] = inc;
    __syncthreads();
    int wo = boff[blockIdx.x];
    for (int j = 0; j < w; ++j) wo += wtot[j];
    if (i < n) {
        int excl = wo + inc - v;
        rowptr[i] = excl;
        cursor[i] = excl;
        dinv[i] = rsqrtf(1.0f + (float)v);
        if (i == n - 1) rowptr[n] = excl + v;
    }
}

__global__ void k_fill(const int* __restrict__ src, const int* __restrict__ dst,
                       int* __restrict__ cursor, int* __restrict__ csr_src, int ne) {
    int e = blockIdx.x * blockDim.x + threadIdx.x;
    if (e < ne) {
        int pos = atomicAdd(&cursor[dst[e]], 1);
        csr_src[pos] = src[e];
    }
}

// ---------------- fused preamble: xbf, wsplit(W1), wsplit(W2), zero sums, zero cnt, counts ----------------
__device__ __forceinline__ void wsplit_one(const float* W, u16* Whi, u16* Wlo, int K, int N, int idx) {
    int n = idx / K, k = idx - n * K;
    float w = W[(size_t)k * N + n];
    u16 hi = f2bf(w);
    u16 lo = f2bf(w - bf2f(hi));
    Whi[idx] = hi;
    Wlo[idx] = lo;
}

// block ranges: [0,XB) xbf | [XB,+128) W1 | [+256) W2 | [+64) sums | [+CB) cnt | [last] counts
__global__ __launch_bounds__(256)
void k_preamble(const float* __restrict__ x, u16* __restrict__ xbf,
                const float* __restrict__ W1, u16* __restrict__ w1hi, u16* __restrict__ w1lo,
                const float* __restrict__ W2, u16* __restrict__ w2hi, u16* __restrict__ w2lo,
                float* __restrict__ sums, int* __restrict__ cnt,
                const int* __restrict__ batch, float* __restrict__ counts) {
    const int XB = (NN * 32 + 255) / 256;        // x as float4: N*128/4 elems
    const int CB = (NN + 255) / 256;
    int b = blockIdx.x, t = threadIdx.x;
    if (b < XB) {
        int i = b * 256 + t;
        if (i < NN * 32) {
            float4 v = ((const float4*)x)[i];
            ushort4 o;
            o.x = f2bf(v.x); o.y = f2bf(v.y); o.z = f2bf(v.z); o.w = f2bf(v.w);
            ((ushort4*)xbf)[i] = o;
        }
        return;
    }
    b -= XB;
    if (b < 128) { wsplit_one(W1, w1hi, w1lo, 128, 256, b * 256 + t); return; }
    b -= 128;
    if (b < 256) { wsplit_one(W2, w2hi, w2lo, 256, 256, b * 256 + t); return; }
    b -= 256;
    if (b < 64) { sums[b * 256 + t] = 0.f; return; }
    b -= 64;
    if (b < CB) {
        int i = b * 256 + t;
        if (i < NN) cnt[i] = 0;
        return;
    }
    b -= CB;
    if (b == 0) {   // counts via binary search on sorted batch
        __shared__ int lb[65];
        if (t <= 64) {
            int lo = 0, hi = NN;
            while (lo < hi) {
                int mid = (lo + hi) >> 1;
                if (batch[mid] < t) lo = mid + 1; else hi = mid;
            }
            lb[t] = lo;
        }
        __syncthreads();
        if (t < 64) counts[t] = (float)(lb[t + 1] - lb[t]);
    }
}

// ---------------- gather aggregation from bf16 source -> single bf16 out ----------------
// agg[d] = dinv[d] * ( sum_{s in in(d)} dinv[s]*hb[s] + dinv[d]*hb[d] )
// Batched indirection: up to 64 neighbor ids + dinv loaded lane-parallel, then
// shfl-broadcast; row gathers issued 4-deep into 2 accumulator banks.
template<int C>   // C=128: u32/lane (2 bf16); C=256: uint2/lane (4 bf16)
__global__ __launch_bounds__(256)
void k_agg_gather(const int* __restrict__ rowptr, const int* __restrict__ csr_src,
                  const float* __restrict__ dinv, const u16* __restrict__ hb,
                  u16* __restrict__ out, int n) {
    constexpr int V = C / 64;   // bf16 per lane (2 or 4)
    int node = (blockIdx.x * blockDim.x + threadIdx.x) >> 6;
    int lane = threadIdx.x & 63;
    if (node >= n) return;
    int beg = rowptr[node], end = rowptr[node + 1];
    int m = end - beg;
    float di = dinv[node];
    float a0[V], a1[V];
    if constexpr (V == 4) {
        uint2 v = ((const uint2*)hb)[(size_t)node * 64 + lane];
        a0[0] = bf2f((u16)v.x) * di; a0[1] = bf2f((u16)(v.x >> 16)) * di;
        a0[2] = bf2f((u16)v.y) * di; a0[3] = bf2f((u16)(v.y >> 16)) * di;
        a1[0] = a1[1] = a1[2] = a1[3] = 0.f;
    } else {
        u32 v = ((const u32*)hb)[(size_t)node * 64 + lane];
        a0[0] = bf2f((u16)v) * di; a0[1] = bf2f((u16)(v >> 16)) * di;
        a1[0] = a1[1] = 0.f;
    }
    for (int base = 0; base < m; base += 64) {
        int c = m - base; if (c > 64) c = 64;
        int sid = 0; float w = 0.f;
        if (lane < c) { sid = csr_src[beg + base + lane]; w = dinv[sid]; }
        int e = 0;
        for (; e + 4 <= c; e += 4) {
            int   s0 = __shfl(sid, e, 64),   s1 = __shfl(sid, e + 1, 64);
            int   s2 = __shfl(sid, e + 2, 64), s3 = __shfl(sid, e + 3, 64);
            float w0 = __shfl(w, e, 64),     w1 = __shfl(w, e + 1, 64);
            float w2 = __shfl(w, e + 2, 64), w3 = __shfl(w, e + 3, 64);
            if constexpr (V == 4) {
                uint2 v0 = ((const uint2*)hb)[(size_t)s0 * 64 + lane];
                uint2 v1 = ((const uint2*)hb)[(size_t)s1 * 64 + lane];
                uint2 v2 = ((const uint2*)hb)[(size_t)s2 * 64 + lane];
                uint2 v3 = ((const uint2*)hb)[(size_t)s3 * 64 + lane];
                a0[0] += bf2f((u16)v0.x) * w0 + bf2f((u16)v2.x) * w2;
                a0[1] += bf2f((u16)(v0.x >> 16)) * w0 + bf2f((u16)(v2.x >> 16)) * w2;
                a0[2] += bf2f((u16)v0.y) * w0 + bf2f((u16)v2.y) * w2;
                a0[3] += bf2f((u16)(v0.y >> 16)) * w0 + bf2f((u16)(v2.y >> 16)) * w2;
                a1[0] += bf2f((u16)v1.x) * w1 + bf2f((u16)v3.x) * w3;
                a1[1] += bf2f((u16)(v1.x >> 16)) * w1 + bf2f((u16)(v3.x >> 16)) * w3;
                a1[2] += bf2f((u16)v1.y) * w1 + bf2f((u16)v3.y) * w3;
                a1[3] += bf2f((u16)(v1.y >> 16)) * w1 + bf2f((u16)(v3.y >> 16)) * w3;
            } else {
                u32 v0 = ((const u32*)hb)[(size_t)s0 * 64 + lane];
                u32 v1 = ((const u32*)hb)[(size_t)s1 * 64 + lane];
                u32 v2 = ((const u32*)hb)[(size_t)s2 * 64 + lane];
                u32 v3 = ((const u32*)hb)[(size_t)s3 * 64 + lane];
                a0[0] += bf2f((u16)v0) * w0 + bf2f((u16)v2) * w2;
                a0[1] += bf2f((u16)(v0 >> 16)) * w0 + bf2f((u16)(v2 >> 16)) * w2;
                a1[0] += bf2f((u16)v1) * w1 + bf2f((u16)v3) * w3;
                a1[1] += bf2f((u16)(v1 >> 16)) * w1 + bf2f((u16)(v3 >> 16)) * w3;
            }
        }
        for (; e < c; ++e) {
            int s0 = __shfl(sid, e, 64);
            float w0 = __shfl(w, e, 64);
            if constexpr (V == 4) {
                uint2 v0 = ((const uint2*)hb)[(size_t)s0 * 64 + lane];
                a0[0] += bf2f((u16)v0.x) * w0; a0[1] += bf2f((u16)(v0.x >> 16)) * w0;
                a0[2] += bf2f((u16)v0.y) * w0; a0[3] += bf2f((u16)(v0.y >> 16)) * w0;
            } else {
                u32 v0 = ((const u32*)hb)[(size_t)s0 * 64 + lane];
                a0[0] += bf2f((u16)v0) * w0; a0[1] += bf2f((u16)(v0 >> 16)) * w0;
            }
        }
    }
    if constexpr (V == 4) {
        uint2 o;
        o.x = (u32)f2bf((a0[0] + a1[0]) * di) | ((u32)f2bf((a0[1] + a1[1]) * di) << 16);
        o.y = (u32)f2bf((a0[2] + a1[2]) * di) | ((u32)f2bf((a0[3] + a1[3]) * di) << 16);
        ((uint2*)out)[(size_t)node * 64 + lane] = o;
    } else {
        ((u32*)out)[(size_t)node * 64 + lane] =
            (u32)f2bf((a0[0] + a1[0]) * di) | ((u32)f2bf((a0[1] + a1[1]) * di) << 16);
    }
}

// ---------------- MFMA GEMM: BM=128, BN=256, BK=32, 512 thr / 8 waves ----------------
// A single-bf16 [M][K]; B = Wt split-bf16 [256][K]. 2 products: A*Bhi + A*Blo.
// Double-buffered LDS (2 x 40KB), stage-early; single barrier per K-step.
__device__ __forceinline__ void stage_tile(u16* ldsbuf, const u16* A, const u16* Bhi,
                                           const u16* Blo, int bm, int k0, int M, int K,
                                           int wid, int lane) {
#pragma unroll
    for (int i = 0; i < 5; ++i) {
        int c = wid + 8 * i;                 // 40 chunks of 1KB
        const u16* gp;
        u32 lbase;
        if (c < 8) {                         // A: 8 chunks
            int s = c * 64 + lane;           // slot 0..511
            int kga = s >> 7, row = s & 127;
            int rg = bm + row; if (rg >= M) rg = M - 1;
            gp = A + (size_t)rg * K + k0 + kga * 8;
            lbase = c * 512;
        } else if (c < 24) {                 // Bhi: 16 chunks
            int cc = c - 8;
            int s = cc * 64 + lane;          // slot 0..1023
            int kgb = s >> 8, col = s & 255;
            gp = Bhi + (size_t)col * K + k0 + kgb * 8;
            lbase = 4096 + cc * 512;
        } else {                             // Blo: 16 chunks
            int cc = c - 24;
            int s = cc * 64 + lane;
            int kgb = s >> 8, col = s & 255;
            gp = Blo + (size_t)col * K + k0 + kgb * 8;
            lbase = 12288 + cc * 512;
        }
        gll16(gp, ldsbuf + lbase);
    }
}

template<bool POOL>
__global__ __launch_bounds__(512)
void k_gemm_mfma(const u16* __restrict__ A, const u16* __restrict__ Bhi,
                 const u16* __restrict__ Blo,
                 const float* __restrict__ bias, u16* __restrict__ out_bf,
                 const int* __restrict__ batch, float* __restrict__ pool,
                 int M, int K) {
    __shared__ u16 lds[2][20480];   // 80KB total
    const int tid = threadIdx.x, lane = tid & 63, wid = tid >> 6;
    const int bm = blockIdx.x * 128;
    const int wr = (wid >> 2) * 64, wc = (wid & 3) * 64;
    const int lr = lane & 15, kg = lane >> 4;

    f32x4 acc[4][4];
#pragma unroll
    for (int i = 0; i < 4; ++i)
#pragma unroll
        for (int j = 0; j < 4; ++j) acc[i][j] = (f32x4){0.f, 0.f, 0.f, 0.f};

    const int nt = K >> 5;
    stage_tile(lds[0], A, Bhi, Blo, bm, 0, M, K, wid, lane);
    __syncthreads();

    for (int t = 0; t < nt; ++t) {
        int cur = t & 1;
        if (t + 1 < nt)
            stage_tile(lds[cur ^ 1], A, Bhi, Blo, bm, (t + 1) << 5, M, K, wid, lane);
        const u16* lb = lds[cur];
        s16x8 a[4];
#pragma unroll
        for (int fm = 0; fm < 4; ++fm)
            a[fm] = *(const s16x8*)&lb[(u32)(kg * 128 + wr + fm * 16 + lr) * 8];
#pragma unroll
        for (int fn = 0; fn < 4; ++fn) {
            int col = wc + fn * 16 + lr;
            u32 sb = (u32)(kg * 256 + col) * 8;
            s16x8 bhi = *(const s16x8*)&lb[4096 + sb];
            s16x8 blo = *(const s16x8*)&lb[12288 + sb];
#pragma unroll
            for (int fm = 0; fm < 4; ++fm) {
                acc[fm][fn] = __builtin_amdgcn_mfma_f32_16x16x32_bf16(a[fm], bhi, acc[fm][fn], 0, 0, 0);
                acc[fm][fn] = __builtin_amdgcn_mfma_f32_16x16x32_bf16(a[fm], blo, acc[fm][fn], 0, 0, 0);
            }
        }
        __syncthreads();
    }

    // epilogue: row = bm + wr + fm*16 + kg*4 + r ; col = wc + fn*16 + lr
#pragma unroll
    for (int fn = 0; fn < 4; ++fn) {
        int col = wc + fn * 16 + lr;
        float bv = bias[col];
        if (!POOL) {
#pragma unroll
            for (int fm = 0; fm < 4; ++fm) {
                int rbase = bm + wr + fm * 16 + kg * 4;
#pragma unroll
                for (int r = 0; r < 4; ++r) {
                    int row = rbase + r;
                    if (row < M)
                        out_bf[(size_t)row * 256 + col] = f2bf(fmaxf(acc[fm][fn][r] + bv, 0.f));
                }
            }
        } else {
            int gcur = -1;
            float run = 0.f;
#pragma unroll
            for (int fm = 0; fm < 4; ++fm) {
                int rbase = bm + wr + fm * 16 + kg * 4;
#pragma unroll
                for (int r = 0; r < 4; ++r) {
                    int row = rbase + r;
                    if (row < M) {
                        int g = batch[row];
                        float v = fmaxf(acc[fm][fn][r] + bv, 0.f);
                        if (g != gcur) {
                            if (gcur >= 0) atomicAdd(&pool[gcur * 256 + col], run);
                            gcur = g;
                            run = 0.f;
                        }
                        run += v;
                    }
                }
            }
            if (gcur >= 0) atomicAdd(&pool[gcur * 256 + col], run);
        }
    }
}

// ---------------- dense head ----------------
__global__ __launch_bounds__(128)
void k_dense(const float* __restrict__ sums, const float* __restrict__ counts,
             const float* __restrict__ W3, const float* __restrict__ b3,
             const float* __restrict__ W4, const float* __restrict__ b4,
             float* __restrict__ out) {
    __shared__ float g[256];
    __shared__ float hid[128];
    int gi = blockIdx.x;
    int t = threadIdx.x;
    float inv = 1.0f / fmaxf(counts[gi], 1.0f);
    for (int c = t; c < 256; c += 128) g[c] = sums[gi * 256 + c] * inv;
    __syncthreads();
    float acc = b3[t];
    for (int k = 0; k < 256; ++k) acc += g[k] * W3[k * 128 + t];
    hid[t] = fmaxf(acc, 0.0f);
    __syncthreads();
    if (t < 10) {
        float o = b4[t];
        for (int k = 0; k < 128; ++k) o += hid[k] * W4[k * 10 + t];
        out[gi * 10 + t] = o;
    }
}

extern "C" void kernel_launch(void* const* d_in, const int* in_sizes, int n_in,
                              void* d_out, int out_size, void* d_ws, size_t ws_size,
                              hipStream_t stream) {
    const float* x   = (const float*)d_in[0];
    const int*  eidx = (const int*)d_in[1];    // [2, NE]
    const int*  batch= (const int*)d_in[2];
    const float* W1 = (const float*)d_in[3];
    const float* b1 = (const float*)d_in[4];
    const float* W2 = (const float*)d_in[5];
    const float* b2 = (const float*)d_in[6];
    const float* W3 = (const float*)d_in[7];
    const float* b3 = (const float*)d_in[8];
    const float* W4 = (const float*)d_in[9];
    const float* b4 = (const float*)d_in[10];
    float* out = (float*)d_out;

    const int N = NN, E = NE, G = NG;
    const int* src = eidx;
    const int* dst = eidx + E;
    const int NB = (N + 255) / 256;

    // workspace layout (256B-aligned slices)
    char* p = (char*)d_ws;
    auto alloc = [&](size_t bytes) { char* r = p; p += (bytes + 255) & ~(size_t)255; return r; };
    u16*   h1bf   = (u16*)alloc((size_t)N * 256 * 2);   // bf16 h1 (gather source for conv2)
    u16*   xbf    = (u16*)alloc((size_t)N * 128 * 2);   // bf16 x  (gather source for conv1)
    float* dinv   = (float*)alloc((size_t)N * 4);
    float* sums   = (float*)alloc((size_t)G * 256 * 4);
    float* counts = (float*)alloc((size_t)G * 4);
    int*   cnt    = (int*)alloc((size_t)N * 4);         // reused as cursor after scan
    int*   rowptr = (int*)alloc((size_t)(N + 1) * 4);
    int*   bsum   = (int*)alloc((size_t)NB * 4);
    int*   csr    = (int*)alloc((size_t)E * 4);
    u16*   agg1   = (u16*)alloc((size_t)N * 128 * 2);   // bf16 aggregated x (GEMM1 A)
    u16*   agg2   = (u16*)alloc((size_t)N * 256 * 2);   // bf16 aggregated h1 (GEMM2 A)
    u16*   w1hi   = (u16*)alloc((size_t)256 * 128 * 2);
    u16*   w1lo   = (u16*)alloc((size_t)256 * 128 * 2);
    u16*   w2hi   = (u16*)alloc((size_t)256 * 256 * 2);
    u16*   w2lo   = (u16*)alloc((size_t)256 * 256 * 2);
    int*   cursor = cnt;

    // fused preamble: xbf, wsplits, zero sums, zero cnt, counts
    const int XB = (NN * 32 + 255) / 256;
    const int CB = (NN + 255) / 256;
    int pre_blocks = XB + 128 + 256 + 64 + CB + 1;
    k_preamble<<<pre_blocks, 256, 0, stream>>>(x, xbf, W1, w1hi, w1lo, W2, w2hi, w2lo,
                                               sums, cnt, batch, counts);

    // CSR build + dinv
    k_hist<<<(E + 255) / 256, 256, 0, stream>>>(dst, cnt, E);
    k_scan1<<<NB, 256, 0, stream>>>(cnt, bsum, N);
    k_scan2<<<1, 256, 0, stream>>>(bsum, NB);
    k_scan3<<<NB, 256, 0, stream>>>(cnt, bsum, rowptr, cursor, dinv, N);
    k_fill<<<(E + 255) / 256, 256, 0, stream>>>(src, dst, cursor, csr, E);

    // conv1: gather-aggregate xbf (128ch) -> bf16 A, MFMA GEMM K=128 -> h1bf (relu+bias)
    k_agg_gather<128><<<(N + 3) / 4, 256, 0, stream>>>(rowptr, csr, dinv, xbf, agg1, N);
    int gblocks = (N + 127) / 128;
    k_gemm_mfma<false><<<gblocks, 512, 0, stream>>>(agg1, w1hi, w1lo, b1, h1bf,
                                                    nullptr, nullptr, N, 128);

    // conv2: gather-aggregate h1bf (256ch) -> bf16 A, MFMA GEMM K=256 fused into pool
    k_agg_gather<256><<<(N + 3) / 4, 256, 0, stream>>>(rowptr, csr, dinv, h1bf, agg2, N);
    k_gemm_mfma<true><<<gblocks, 512, 0, stream>>>(agg2, w2hi, w2lo, b2, nullptr,
                                                   batch, sums, N, 256);

    // dense head
    k_dense<<<G, 128, 0, stream>>>(sums, counts, W3, b3, W4, b4, out);
}

// Round 8
// 223.971 us; speedup vs baseline: 14.9472x; 1.0801x over previous
//
#include <hip/hip_runtime.h>

typedef unsigned short u16;
typedef unsigned int u32;
typedef __attribute__((ext_vector_type(8))) short s16x8;
typedef __attribute__((ext_vector_type(4))) float f32x4;

#define NN 50000
#define NE 600000
#define NG 64

__device__ __forceinline__ u16 f2bf(float f) {
    u32 u = __float_as_uint(f);
    u32 r = (u + 0x7fffu + ((u >> 16) & 1u)) >> 16;
    return (u16)r;
}
__device__ __forceinline__ float bf2f(u16 h) {
    return __uint_as_float(((u32)h) << 16);
}
__device__ __forceinline__ void gll16(const void* g, void* l) {
    __builtin_amdgcn_global_load_lds((const __attribute__((address_space(1))) u32*)g,
                                     (__attribute__((address_space(3))) u32*)l, 16, 0, 0);
}

// ---------------- CSR build ----------------
__global__ void k_hist(const int* __restrict__ dst, int* __restrict__ cnt, int ne) {
    int e = blockIdx.x * blockDim.x + threadIdx.x;
    if (e < ne) atomicAdd(&cnt[dst[e]], 1);
}

__global__ __launch_bounds__(256)
void k_scan1(const int* __restrict__ cnt, int* __restrict__ bsum, int n) {
    int i = blockIdx.x * 256 + threadIdx.x;
    int v = (i < n) ? cnt[i] : 0;
#pragma unroll
    for (int off = 32; off > 0; off >>= 1) v += __shfl_down(v, off, 64);
    __shared__ int ws[4];
    int lane = threadIdx.x & 63, w = threadIdx.x >> 6;
    if (lane == 0) ws[w] = v;
    __syncthreads();
    if (threadIdx.x == 0) bsum[blockIdx.x] = ws[0] + ws[1] + ws[2] + ws[3];
}

__global__ __launch_bounds__(256)
void k_scan2(int* __restrict__ bsum, int nb) {
    int t = threadIdx.x;
    int v = (t < nb) ? bsum[t] : 0;
    int lane = t & 63, w = t >> 6;
    int inc = v;
#pragma unroll
    for (int off = 1; off < 64; off <<= 1) {
        int x = __shfl_up(inc, off, 64);
        if (lane >= off) inc += x;
    }
    __shared__ int wtot[4];
    if (lane == 63) wtot[w] = inc;
    __syncthreads();
    int wo = 0;
    for (int j = 0; j < w; ++j) wo += wtot[j];
    if (t < nb) bsum[t] = wo + inc - v;   // exclusive
}

__global__ __launch_bounds__(256)
void k_scan3(const int* __restrict__ cnt, const int* __restrict__ boff,
             int* __restrict__ rowptr, int* __restrict__ cursor,
             float* __restrict__ dinv, int n) {
    int i = blockIdx.x * 256 + threadIdx.x;
    int v = (i < n) ? cnt[i] : 0;
    int lane = threadIdx.x & 63, w = threadIdx.x >> 6;
    int inc = v;
#pragma unroll
    for (int off = 1; off < 64; off <<= 1) {
        int x = __shfl_up(inc, off, 64);
        if (lane >= off) inc += x;
    }
    __shared__ int wtot[4];
    if (lane == 63) wtot[w] = inc;
    __syncthreads();
    int wo = boff[blockIdx.x];
    for (int j = 0; j < w; ++j) wo += wtot[j];
    if (i < n) {
        int excl = wo + inc - v;
        rowptr[i] = excl;
        cursor[i] = excl;
        dinv[i] = rsqrtf(1.0f + (float)v);
        if (i == n - 1) rowptr[n] = excl + v;
    }
}

__global__ void k_fill(const int* __restrict__ src, const int* __restrict__ dst,
                       int* __restrict__ cursor, int* __restrict__ csr_src, int ne) {
    int e = blockIdx.x * blockDim.x + threadIdx.x;
    if (e < ne) {
        int pos = atomicAdd(&cursor[dst[e]], 1);
        csr_src[pos] = src[e];
    }
}

// ---------------- fused preamble ----------------
// Weight split is stored PRE-TILED: wt[kgrp][n][8] with k = kgrp*8 + j
// (kgrp = kb*4+kg for BK=32 tiles) so GEMM B-fragments are contiguous 16B/lane.
__device__ __forceinline__ void wsplit_tiled(const float* __restrict__ W,
                                             u16* __restrict__ hi, u16* __restrict__ lo,
                                             int gid) {
    int n = gid & 255, kgrp = gid >> 8;
    int kbase = kgrp * 8;
#pragma unroll
    for (int j = 0; j < 8; ++j) {
        float w = W[(size_t)(kbase + j) * 256 + n];
        u16 h = f2bf(w);
        hi[(size_t)gid * 8 + j] = h;
        lo[(size_t)gid * 8 + j] = f2bf(w - bf2f(h));
    }
}

// block ranges: [0,XB) xbf | [16) W1 | [32) W2 | [64) sums | [CB) cnt | [1] counts
__global__ __launch_bounds__(256)
void k_preamble(const float* __restrict__ x, u16* __restrict__ xbf,
                const float* __restrict__ W1, u16* __restrict__ w1hi, u16* __restrict__ w1lo,
                const float* __restrict__ W2, u16* __restrict__ w2hi, u16* __restrict__ w2lo,
                float* __restrict__ sums, int* __restrict__ cnt,
                const int* __restrict__ batch, float* __restrict__ counts) {
    const int XB = (NN * 32 + 255) / 256;        // x as float4: N*128/4 elems
    const int CB = (NN + 255) / 256;
    int b = blockIdx.x, t = threadIdx.x;
    if (b < XB) {
        int i = b * 256 + t;
        if (i < NN * 32) {
            float4 v = ((const float4*)x)[i];
            ushort4 o;
            o.x = f2bf(v.x); o.y = f2bf(v.y); o.z = f2bf(v.z); o.w = f2bf(v.w);
            ((ushort4*)xbf)[i] = o;
        }
        return;
    }
    b -= XB;
    if (b < 16) { wsplit_tiled(W1, w1hi, w1lo, b * 256 + t); return; }   // 4096 groups
    b -= 16;
    if (b < 32) { wsplit_tiled(W2, w2hi, w2lo, b * 256 + t); return; }   // 8192 groups
    b -= 32;
    if (b < 64) { sums[b * 256 + t] = 0.f; return; }
    b -= 64;
    if (b < CB) {
        int i = b * 256 + t;
        if (i < NN) cnt[i] = 0;
        return;
    }
    b -= CB;
    if (b == 0) {   // counts via binary search on sorted batch
        __shared__ int lb[65];
        if (t <= 64) {
            int lo = 0, hi = NN;
            while (lo < hi) {
                int mid = (lo + hi) >> 1;
                if (batch[mid] < t) lo = mid + 1; else hi = mid;
            }
            lb[t] = lo;
        }
        __syncthreads();
        if (t < 64) counts[t] = (float)(lb[t + 1] - lb[t]);
    }
}

// ---------------- gather aggregation from bf16 source -> single bf16 out ----------------
template<int C>   // C=128: u32/lane (2 bf16); C=256: uint2/lane (4 bf16)
__global__ __launch_bounds__(256)
void k_agg_gather(const int* __restrict__ rowptr, const int* __restrict__ csr_src,
                  const float* __restrict__ dinv, const u16* __restrict__ hb,
                  u16* __restrict__ out, int n) {
    constexpr int V = C / 64;   // bf16 per lane (2 or 4)
    int node = (blockIdx.x * blockDim.x + threadIdx.x) >> 6;
    int lane = threadIdx.x & 63;
    if (node >= n) return;
    int beg = rowptr[node], end = rowptr[node + 1];
    int m = end - beg;
    float di = dinv[node];
    float a0[V], a1[V];
    if constexpr (V == 4) {
        uint2 v = ((const uint2*)hb)[(size_t)node * 64 + lane];
        a0[0] = bf2f((u16)v.x) * di; a0[1] = bf2f((u16)(v.x >> 16)) * di;
        a0[2] = bf2f((u16)v.y) * di; a0[3] = bf2f((u16)(v.y >> 16)) * di;
        a1[0] = a1[1] = a1[2] = a1[3] = 0.f;
    } else {
        u32 v = ((const u32*)hb)[(size_t)node * 64 + lane];
        a0[0] = bf2f((u16)v) * di; a0[1] = bf2f((u16)(v >> 16)) * di;
        a1[0] = a1[1] = 0.f;
    }
    for (int base = 0; base < m; base += 64) {
        int c = m - base; if (c > 64) c = 64;
        int sid = 0; float w = 0.f;
        if (lane < c) { sid = csr_src[beg + base + lane]; w = dinv[sid]; }
        int e = 0;
        for (; e + 4 <= c; e += 4) {
            int   s0 = __shfl(sid, e, 64),   s1 = __shfl(sid, e + 1, 64);
            int   s2 = __shfl(sid, e + 2, 64), s3 = __shfl(sid, e + 3, 64);
            float w0 = __shfl(w, e, 64),     w1 = __shfl(w, e + 1, 64);
            float w2 = __shfl(w, e + 2, 64), w3 = __shfl(w, e + 3, 64);
            if constexpr (V == 4) {
                uint2 v0 = ((const uint2*)hb)[(size_t)s0 * 64 + lane];
                uint2 v1 = ((const uint2*)hb)[(size_t)s1 * 64 + lane];
                uint2 v2 = ((const uint2*)hb)[(size_t)s2 * 64 + lane];
                uint2 v3 = ((const uint2*)hb)[(size_t)s3 * 64 + lane];
                a0[0] += bf2f((u16)v0.x) * w0 + bf2f((u16)v2.x) * w2;
                a0[1] += bf2f((u16)(v0.x >> 16)) * w0 + bf2f((u16)(v2.x >> 16)) * w2;
                a0[2] += bf2f((u16)v0.y) * w0 + bf2f((u16)v2.y) * w2;
                a0[3] += bf2f((u16)(v0.y >> 16)) * w0 + bf2f((u16)(v2.y >> 16)) * w2;
                a1[0] += bf2f((u16)v1.x) * w1 + bf2f((u16)v3.x) * w3;
                a1[1] += bf2f((u16)(v1.x >> 16)) * w1 + bf2f((u16)(v3.x >> 16)) * w3;
                a1[2] += bf2f((u16)v1.y) * w1 + bf2f((u16)v3.y) * w3;
                a1[3] += bf2f((u16)(v1.y >> 16)) * w1 + bf2f((u16)(v3.y >> 16)) * w3;
            } else {
                u32 v0 = ((const u32*)hb)[(size_t)s0 * 64 + lane];
                u32 v1 = ((const u32*)hb)[(size_t)s1 * 64 + lane];
                u32 v2 = ((const u32*)hb)[(size_t)s2 * 64 + lane];
                u32 v3 = ((const u32*)hb)[(size_t)s3 * 64 + lane];
                a0[0] += bf2f((u16)v0) * w0 + bf2f((u16)v2) * w2;
                a0[1] += bf2f((u16)(v0 >> 16)) * w0 + bf2f((u16)(v2 >> 16)) * w2;
                a1[0] += bf2f((u16)v1) * w1 + bf2f((u16)v3) * w3;
                a1[1] += bf2f((u16)(v1 >> 16)) * w1 + bf2f((u16)(v3 >> 16)) * w3;
            }
        }
        for (; e < c; ++e) {
            int s0 = __shfl(sid, e, 64);
            float w0 = __shfl(w, e, 64);
            if constexpr (V == 4) {
                uint2 v0 = ((const uint2*)hb)[(size_t)s0 * 64 + lane];
                a0[0] += bf2f((u16)v0.x) * w0; a0[1] += bf2f((u16)(v0.x >> 16)) * w0;
                a0[2] += bf2f((u16)v0.y) * w0; a0[3] += bf2f((u16)(v0.y >> 16)) * w0;
            } else {
                u32 v0 = ((const u32*)hb)[(size_t)s0 * 64 + lane];
                a0[0] += bf2f((u16)v0) * w0; a0[1] += bf2f((u16)(v0 >> 16)) * w0;
            }
        }
    }
    if constexpr (V == 4) {
        uint2 o;
        o.x = (u32)f2bf((a0[0] + a1[0]) * di) | ((u32)f2bf((a0[1] + a1[1]) * di) << 16);
        o.y = (u32)f2bf((a0[2] + a1[2]) * di) | ((u32)f2bf((a0[3] + a1[3]) * di) << 16);
        ((uint2*)out)[(size_t)node * 64 + lane] = o;
    } else {
        ((u32*)out)[(size_t)node * 64 + lane] =
            (u32)f2bf((a0[0] + a1[0]) * di) | ((u32)f2bf((a0[1] + a1[1]) * di) << 16);
    }
}

// ---------------- MFMA GEMM: BM=128, BN=256, BK=32, 512 thr / 8 waves ----------------
// A single-bf16 [M][K] staged in LDS (16KB dbuf), m97-style 64B-granular chunks with
// XOR source-slot swizzle (linear LDS dest, per-lane swizzled global src -> <=2-way
// ds_read conflicts). B = pre-tiled weight split, read straight to VGPRs from L2.
template<bool POOL>
__global__ __launch_bounds__(512, 4)
void k_gemm_mfma(const u16* __restrict__ A, const u16* __restrict__ Bhi,
                 const u16* __restrict__ Blo,
                 const float* __restrict__ bias, u16* __restrict__ out_bf,
                 const int* __restrict__ batch, float* __restrict__ pool,
                 int M, int K) {
    __shared__ u16 ldsA[2][4096];   // 2 x 8KB: [128 rows][4 slots of 8 bf16]
    const int tid = threadIdx.x, lane = tid & 63, wid = tid >> 6;
    const int bm = blockIdx.x * 128;
    const int wr = (wid >> 2) * 64, wc = (wid & 3) * 64;
    const int lr = lane & 15, kg = lane >> 4;

    // per-wave A-stage addressing: wave wid stages rows wid*16..+15 (1KB chunk)
    const int srow = wid * 16 + (lane >> 2);            // local row 0..127
    const int sslot = lane & 3;
    const int ssw = (srow ^ (srow >> 2)) & 3;
    int srg = bm + srow; if (srg >= M) srg = M - 1;
    const u16* sbase = A + (size_t)srg * K + ((sslot ^ ssw) << 3);

    f32x4 acc[4][4];
#pragma unroll
    for (int i = 0; i < 4; ++i)
#pragma unroll
        for (int j = 0; j < 4; ++j) acc[i][j] = (f32x4){0.f, 0.f, 0.f, 0.f};

    const int nt = K >> 5;
    gll16(sbase, &ldsA[0][wid * 512]);     // prologue: stage tile 0
    __syncthreads();

    for (int t = 0; t < nt; ++t) {
        int cur = t & 1;
        if (t + 1 < nt)
            gll16(sbase + ((t + 1) << 5), &ldsA[cur ^ 1][wid * 512]);

        // B fragments straight from L2 (pre-tiled: contiguous 256B per 16-lane group)
        s16x8 bh[4], bl[4];
#pragma unroll
        for (int fn = 0; fn < 4; ++fn) {
            size_t off = ((size_t)((t << 2) + kg) * 256 + wc + fn * 16 + lr) * 8;
            bh[fn] = *(const s16x8*)&Bhi[off];
            bl[fn] = *(const s16x8*)&Blo[off];
        }
        // A fragments from LDS (swizzled slots)
        const u16* lb = ldsA[cur];
        s16x8 a[4];
#pragma unroll
        for (int fm = 0; fm < 4; ++fm) {
            int r = wr + fm * 16 + lr;
            a[fm] = *(const s16x8*)&lb[r * 32 + ((kg ^ ((r ^ (r >> 2)) & 3)) << 3)];
        }
#pragma unroll
        for (int fn = 0; fn < 4; ++fn)
#pragma unroll
            for (int fm = 0; fm < 4; ++fm) {
                acc[fm][fn] = __builtin_amdgcn_mfma_f32_16x16x32_bf16(a[fm], bh[fn], acc[fm][fn], 0, 0, 0);
                acc[fm][fn] = __builtin_amdgcn_mfma_f32_16x16x32_bf16(a[fm], bl[fn], acc[fm][fn], 0, 0, 0);
            }
        __syncthreads();
    }

    // epilogue: row = bm + wr + fm*16 + kg*4 + r ; col = wc + fn*16 + lr
#pragma unroll
    for (int fn = 0; fn < 4; ++fn) {
        int col = wc + fn * 16 + lr;
        float bv = bias[col];
        if (!POOL) {
#pragma unroll
            for (int fm = 0; fm < 4; ++fm) {
                int rbase = bm + wr + fm * 16 + kg * 4;
#pragma unroll
                for (int r = 0; r < 4; ++r) {
                    int row = rbase + r;
                    if (row < M)
                        out_bf[(size_t)row * 256 + col] = f2bf(fmaxf(acc[fm][fn][r] + bv, 0.f));
                }
            }
        } else {
            int gcur = -1;
            float run = 0.f;
#pragma unroll
            for (int fm = 0; fm < 4; ++fm) {
                int rbase = bm + wr + fm * 16 + kg * 4;
#pragma unroll
                for (int r = 0; r < 4; ++r) {
                    int row = rbase + r;
                    if (row < M) {
                        int g = batch[row];
                        float v = fmaxf(acc[fm][fn][r] + bv, 0.f);
                        if (g != gcur) {
                            if (gcur >= 0) atomicAdd(&pool[gcur * 256 + col], run);
                            gcur = g;
                            run = 0.f;
                        }
                        run += v;
                    }
                }
            }
            if (gcur >= 0) atomicAdd(&pool[gcur * 256 + col], run);
        }
    }
}

// ---------------- dense head ----------------
__global__ __launch_bounds__(128)
void k_dense(const float* __restrict__ sums, const float* __restrict__ counts,
             const float* __restrict__ W3, const float* __restrict__ b3,
             const float* __restrict__ W4, const float* __restrict__ b4,
             float* __restrict__ out) {
    __shared__ float g[256];
    __shared__ float hid[128];
    int gi = blockIdx.x;
    int t = threadIdx.x;
    float inv = 1.0f / fmaxf(counts[gi], 1.0f);
    for (int c = t; c < 256; c += 128) g[c] = sums[gi * 256 + c] * inv;
    __syncthreads();
    float acc = b3[t];
    for (int k = 0; k < 256; ++k) acc += g[k] * W3[k * 128 + t];
    hid[t] = fmaxf(acc, 0.0f);
    __syncthreads();
    if (t < 10) {
        float o = b4[t];
        for (int k = 0; k < 128; ++k) o += hid[k] * W4[k * 10 + t];
        out[gi * 10 + t] = o;
    }
}

extern "C" void kernel_launch(void* const* d_in, const int* in_sizes, int n_in,
                              void* d_out, int out_size, void* d_ws, size_t ws_size,
                              hipStream_t stream) {
    const float* x   = (const float*)d_in[0];
    const int*  eidx = (const int*)d_in[1];    // [2, NE]
    const int*  batch= (const int*)d_in[2];
    const float* W1 = (const float*)d_in[3];
    const float* b1 = (const float*)d_in[4];
    const float* W2 = (const float*)d_in[5];
    const float* b2 = (const float*)d_in[6];
    const float* W3 = (const float*)d_in[7];
    const float* b3 = (const float*)d_in[8];
    const float* W4 = (const float*)d_in[9];
    const float* b4 = (const float*)d_in[10];
    float* out = (float*)d_out;

    const int N = NN, E = NE, G = NG;
    const int* src = eidx;
    const int* dst = eidx + E;
    const int NB = (N + 255) / 256;

    // workspace layout (256B-aligned slices)
    char* p = (char*)d_ws;
    auto alloc = [&](size_t bytes) { char* r = p; p += (bytes + 255) & ~(size_t)255; return r; };
    u16*   h1bf   = (u16*)alloc((size_t)N * 256 * 2);   // bf16 h1 (gather source for conv2)
    u16*   xbf    = (u16*)alloc((size_t)N * 128 * 2);   // bf16 x  (gather source for conv1)
    float* dinv   = (float*)alloc((size_t)N * 4);
    float* sums   = (float*)alloc((size_t)G * 256 * 4);
    float* counts = (float*)alloc((size_t)G * 4);
    int*   cnt    = (int*)alloc((size_t)N * 4);         // reused as cursor after scan
    int*   rowptr = (int*)alloc((size_t)(N + 1) * 4);
    int*   bsum   = (int*)alloc((size_t)NB * 4);
    int*   csr    = (int*)alloc((size_t)E * 4);
    u16*   agg1   = (u16*)alloc((size_t)N * 128 * 2);   // bf16 aggregated x (GEMM1 A)
    u16*   agg2   = (u16*)alloc((size_t)N * 256 * 2);   // bf16 aggregated h1 (GEMM2 A)
    u16*   w1hi   = (u16*)alloc((size_t)256 * 128 * 2); // pre-tiled [kgrp][n][8]
    u16*   w1lo   = (u16*)alloc((size_t)256 * 128 * 2);
    u16*   w2hi   = (u16*)alloc((size_t)256 * 256 * 2);
    u16*   w2lo   = (u16*)alloc((size_t)256 * 256 * 2);
    int*   cursor = cnt;

    // fused preamble: xbf, tiled wsplits, zero sums, zero cnt, counts
    const int XB = (NN * 32 + 255) / 256;
    const int CB = (NN + 255) / 256;
    int pre_blocks = XB + 16 + 32 + 64 + CB + 1;
    k_preamble<<<pre_blocks, 256, 0, stream>>>(x, xbf, W1, w1hi, w1lo, W2, w2hi, w2lo,
                                               sums, cnt, batch, counts);

    // CSR build + dinv
    k_hist<<<(E + 255) / 256, 256, 0, stream>>>(dst, cnt, E);
    k_scan1<<<NB, 256, 0, stream>>>(cnt, bsum, N);
    k_scan2<<<1, 256, 0, stream>>>(bsum, NB);
    k_scan3<<<NB, 256, 0, stream>>>(cnt, bsum, rowptr, cursor, dinv, N);
    k_fill<<<(E + 255) / 256, 256, 0, stream>>>(src, dst, cursor, csr, E);

    // conv1: gather-aggregate xbf (128ch) -> bf16 A, MFMA GEMM K=128 -> h1bf (relu+bias)
    k_agg_gather<128><<<(N + 3) / 4, 256, 0, stream>>>(rowptr, csr, dinv, xbf, agg1, N);
    int gblocks = (N + 127) / 128;
    k_gemm_mfma<false><<<gblocks, 512, 0, stream>>>(agg1, w1hi, w1lo, b1, h1bf,
                                                    nullptr, nullptr, N, 128);

    // conv2: gather-aggregate h1bf (256ch) -> bf16 A, MFMA GEMM K=256 fused into pool
    k_agg_gather<256><<<(N + 3) / 4, 256, 0, stream>>>(rowptr, csr, dinv, h1bf, agg2, N);
    k_gemm_mfma<true><<<gblocks, 512, 0, stream>>>(agg2, w2hi, w2lo, b2, nullptr,
                                                   batch, sums, N, 256);

    // dense head
    k_dense<<<G, 128, 0, stream>>>(sums, counts, W3, b3, W4, b4, out);
}

// Round 9
// 221.226 us; speedup vs baseline: 15.1327x; 1.0124x over previous
//
#include <hip/hip_runtime.h>

typedef unsigned short u16;
typedef unsigned int u32;
typedef __attribute__((ext_vector_type(8))) short s16x8;
typedef __attribute__((ext_vector_type(4))) float f32x4;

#define NN 50000
#define NE 600000
#define NG 64

__device__ __forceinline__ u16 f2bf(float f) {
    u32 u = __float_as_uint(f);
    u32 r = (u + 0x7fffu + ((u >> 16) & 1u)) >> 16;
    return (u16)r;
}
__device__ __forceinline__ float bf2f(u16 h) {
    return __uint_as_float(((u32)h) << 16);
}
__device__ __forceinline__ void gll16(const void* g, void* l) {
    __builtin_amdgcn_global_load_lds((const __attribute__((address_space(1))) u32*)g,
                                     (__attribute__((address_space(3))) u32*)l, 16, 0, 0);
}

// ---------------- CSR build ----------------
__global__ void k_hist(const int* __restrict__ dst, int* __restrict__ cnt, int ne) {
    int e = blockIdx.x * blockDim.x + threadIdx.x;
    if (e < ne) atomicAdd(&cnt[dst[e]], 1);
}

__global__ __launch_bounds__(256)
void k_scan1(const int* __restrict__ cnt, int* __restrict__ bsum, int n) {
    int i = blockIdx.x * 256 + threadIdx.x;
    int v = (i < n) ? cnt[i] : 0;
#pragma unroll
    for (int off = 32; off > 0; off >>= 1) v += __shfl_down(v, off, 64);
    __shared__ int ws[4];
    int lane = threadIdx.x & 63, w = threadIdx.x >> 6;
    if (lane == 0) ws[w] = v;
    __syncthreads();
    if (threadIdx.x == 0) bsum[blockIdx.x] = ws[0] + ws[1] + ws[2] + ws[3];
}

__global__ __launch_bounds__(256)
void k_scan2(int* __restrict__ bsum, int nb) {
    int t = threadIdx.x;
    int v = (t < nb) ? bsum[t] : 0;
    int lane = t & 63, w = t >> 6;
    int inc = v;
#pragma unroll
    for (int off = 1; off < 64; off <<= 1) {
        int x = __shfl_up(inc, off, 64);
        if (lane >= off) inc += x;
    }
    __shared__ int wtot[4];
    if (lane == 63) wtot[w] = inc;
    __syncthreads();
    int wo = 0;
    for (int j = 0; j < w; ++j) wo += wtot[j];
    if (t < nb) bsum[t] = wo + inc - v;   // exclusive
}

__global__ __launch_bounds__(256)
void k_scan3(const int* __restrict__ cnt, const int* __restrict__ boff,
             int* __restrict__ rowptr, int* __restrict__ cursor,
             float* __restrict__ dinv, int n) {
    int i = blockIdx.x * 256 + threadIdx.x;
    int v = (i < n) ? cnt[i] : 0;
    int lane = threadIdx.x & 63, w = threadIdx.x >> 6;
    int inc = v;
#pragma unroll
    for (int off = 1; off < 64; off <<= 1) {
        int x = __shfl_up(inc, off, 64);
        if (lane >= off) inc += x;
    }
    __shared__ int wtot[4];
    if (lane == 63) wtot[w] = inc;
    __syncthreads();
    int wo = boff[blockIdx.x];
    for (int j = 0; j < w; ++j) wo += wtot[j];
    if (i < n) {
        int excl = wo + inc - v;
        rowptr[i] = excl;
        cursor[i] = excl;
        dinv[i] = rsqrtf(1.0f + (float)v);
        if (i == n - 1) rowptr[n] = excl + v;
    }
}

__global__ void k_fill(const int* __restrict__ src, const int* __restrict__ dst,
                       int* __restrict__ cursor, int* __restrict__ csr_src, int ne) {
    int e = blockIdx.x * blockDim.x + threadIdx.x;
    if (e < ne) {
        int pos = atomicAdd(&cursor[dst[e]], 1);
        csr_src[pos] = src[e];
    }
}

// ---------------- fused preamble ----------------
// Weight split is stored PRE-TILED: wt[kgrp][n][8] with k = kgrp*8 + j
__device__ __forceinline__ void wsplit_tiled(const float* __restrict__ W,
                                             u16* __restrict__ hi, u16* __restrict__ lo,
                                             int gid) {
    int n = gid & 255, kgrp = gid >> 8;
    int kbase = kgrp * 8;
#pragma unroll
    for (int j = 0; j < 8; ++j) {
        float w = W[(size_t)(kbase + j) * 256 + n];
        u16 h = f2bf(w);
        hi[(size_t)gid * 8 + j] = h;
        lo[(size_t)gid * 8 + j] = f2bf(w - bf2f(h));
    }
}

// block ranges: [0,XB) xbf | [16) W1 | [32) W2 | [64) sums | [CB) cnt | [1] counts
__global__ __launch_bounds__(256)
void k_preamble(const float* __restrict__ x, u16* __restrict__ xbf,
                const float* __restrict__ W1, u16* __restrict__ w1hi, u16* __restrict__ w1lo,
                const float* __restrict__ W2, u16* __restrict__ w2hi, u16* __restrict__ w2lo,
                float* __restrict__ sums, int* __restrict__ cnt,
                const int* __restrict__ batch, float* __restrict__ counts) {
    const int XB = (NN * 32 + 255) / 256;        // x as float4: N*128/4 elems
    const int CB = (NN + 255) / 256;
    int b = blockIdx.x, t = threadIdx.x;
    if (b < XB) {
        int i = b * 256 + t;
        if (i < NN * 32) {
            float4 v = ((const float4*)x)[i];
            ushort4 o;
            o.x = f2bf(v.x); o.y = f2bf(v.y); o.z = f2bf(v.z); o.w = f2bf(v.w);
            ((ushort4*)xbf)[i] = o;
        }
        return;
    }
    b -= XB;
    if (b < 16) { wsplit_tiled(W1, w1hi, w1lo, b * 256 + t); return; }   // 4096 groups
    b -= 16;
    if (b < 32) { wsplit_tiled(W2, w2hi, w2lo, b * 256 + t); return; }   // 8192 groups
    b -= 32;
    if (b < 64) { sums[b * 256 + t] = 0.f; return; }
    b -= 64;
    if (b < CB) {
        int i = b * 256 + t;
        if (i < NN) cnt[i] = 0;
        return;
    }
    b -= CB;
    if (b == 0) {   // counts via binary search on sorted batch
        __shared__ int lb[65];
        if (t <= 64) {
            int lo = 0, hi = NN;
            while (lo < hi) {
                int mid = (lo + hi) >> 1;
                if (batch[mid] < t) lo = mid + 1; else hi = mid;
            }
            lb[t] = lo;
        }
        __syncthreads();
        if (t < 64) counts[t] = (float)(lb[t + 1] - lb[t]);
    }
}

// ---------------- gather aggregation: 2 nodes/wave, 32 lanes/node ----------------
// agg[d] = dinv[d] * ( sum_{s in in(d)} dinv[s]*hb[s] + dinv[d]*hb[d] )
__device__ __forceinline__ void fma8(float* a, const uint4& v, float w) {
    a[0] += bf2f((u16)v.x) * w; a[1] += bf2f((u16)(v.x >> 16)) * w;
    a[2] += bf2f((u16)v.y) * w; a[3] += bf2f((u16)(v.y >> 16)) * w;
    a[4] += bf2f((u16)v.z) * w; a[5] += bf2f((u16)(v.z >> 16)) * w;
    a[6] += bf2f((u16)v.w) * w; a[7] += bf2f((u16)(v.w >> 16)) * w;
}
__device__ __forceinline__ void fma4(float* a, const uint2& v, float w) {
    a[0] += bf2f((u16)v.x) * w; a[1] += bf2f((u16)(v.x >> 16)) * w;
    a[2] += bf2f((u16)v.y) * w; a[3] += bf2f((u16)(v.y >> 16)) * w;
}

template<int C>   // C=256: uint4/lane (8 bf16); C=128: uint2/lane (4 bf16)
__global__ __launch_bounds__(256)
void k_agg_gather(const int* __restrict__ rowptr, const int* __restrict__ csr_src,
                  const float* __restrict__ dinv, const u16* __restrict__ hb,
                  u16* __restrict__ out, int n) {
    constexpr int VL = C / 32;           // bf16 per lane (8 or 4)
    int tid = threadIdx.x;
    int node = (blockIdx.x * 256 + tid) >> 5;
    if (node >= n) return;
    int sl = tid & 31;                   // lane within node's 32-lane group
    int hbase = tid & 32;                // this half's lane base within the wave
    int beg = rowptr[node], end = rowptr[node + 1];
    int m = end - beg;
    float di = dinv[node];
    float a0[VL], a1[VL];
    if constexpr (VL == 8) {
        uint4 v = ((const uint4*)hb)[(size_t)node * 32 + sl];
#pragma unroll
        for (int i = 0; i < 8; ++i) a1[i] = 0.f;
        a0[0] = bf2f((u16)v.x) * di; a0[1] = bf2f((u16)(v.x >> 16)) * di;
        a0[2] = bf2f((u16)v.y) * di; a0[3] = bf2f((u16)(v.y >> 16)) * di;
        a0[4] = bf2f((u16)v.z) * di; a0[5] = bf2f((u16)(v.z >> 16)) * di;
        a0[6] = bf2f((u16)v.w) * di; a0[7] = bf2f((u16)(v.w >> 16)) * di;
    } else {
        uint2 v = ((const uint2*)hb)[(size_t)node * 32 + sl];
#pragma unroll
        for (int i = 0; i < 4; ++i) a1[i] = 0.f;
        a0[0] = bf2f((u16)v.x) * di; a0[1] = bf2f((u16)(v.x >> 16)) * di;
        a0[2] = bf2f((u16)v.y) * di; a0[3] = bf2f((u16)(v.y >> 16)) * di;
    }
    for (int base = 0; base < m; base += 32) {
        int c = m - base; if (c > 32) c = 32;
        int sid = 0; float w = 0.f;      // padding lanes: node 0 with weight 0 (harmless)
        if (sl < c) { sid = csr_src[beg + base + sl]; w = dinv[sid]; }
        int cr = (c + 3) & ~3;           // round up: no serial tail
        for (int e = 0; e < cr; e += 4) {
            int   s0 = __shfl(sid, hbase + e, 64),     s1 = __shfl(sid, hbase + e + 1, 64);
            int   s2 = __shfl(sid, hbase + e + 2, 64), s3 = __shfl(sid, hbase + e + 3, 64);
            float w0 = __shfl(w, hbase + e, 64),       w1 = __shfl(w, hbase + e + 1, 64);
            float w2 = __shfl(w, hbase + e + 2, 64),   w3 = __shfl(w, hbase + e + 3, 64);
            if constexpr (VL == 8) {
                uint4 r0 = ((const uint4*)hb)[(size_t)s0 * 32 + sl];
                uint4 r1 = ((const uint4*)hb)[(size_t)s1 * 32 + sl];
                uint4 r2 = ((const uint4*)hb)[(size_t)s2 * 32 + sl];
                uint4 r3 = ((const uint4*)hb)[(size_t)s3 * 32 + sl];
                fma8(a0, r0, w0); fma8(a1, r1, w1); fma8(a0, r2, w2); fma8(a1, r3, w3);
            } else {
                uint2 r0 = ((const uint2*)hb)[(size_t)s0 * 32 + sl];
                uint2 r1 = ((const uint2*)hb)[(size_t)s1 * 32 + sl];
                uint2 r2 = ((const uint2*)hb)[(size_t)s2 * 32 + sl];
                uint2 r3 = ((const uint2*)hb)[(size_t)s3 * 32 + sl];
                fma4(a0, r0, w0); fma4(a1, r1, w1); fma4(a0, r2, w2); fma4(a1, r3, w3);
            }
        }
    }
    if constexpr (VL == 8) {
        uint4 o;
        o.x = (u32)f2bf((a0[0] + a1[0]) * di) | ((u32)f2bf((a0[1] + a1[1]) * di) << 16);
        o.y = (u32)f2bf((a0[2] + a1[2]) * di) | ((u32)f2bf((a0[3] + a1[3]) * di) << 16);
        o.z = (u32)f2bf((a0[4] + a1[4]) * di) | ((u32)f2bf((a0[5] + a1[5]) * di) << 16);
        o.w = (u32)f2bf((a0[6] + a1[6]) * di) | ((u32)f2bf((a0[7] + a1[7]) * di) << 16);
        ((uint4*)out)[(size_t)node * 32 + sl] = o;
    } else {
        uint2 o;
        o.x = (u32)f2bf((a0[0] + a1[0]) * di) | ((u32)f2bf((a0[1] + a1[1]) * di) << 16);
        o.y = (u32)f2bf((a0[2] + a1[2]) * di) | ((u32)f2bf((a0[3] + a1[3]) * di) << 16);
        ((uint2*)out)[(size_t)node * 32 + sl] = o;
    }
}

// ---------------- MFMA GEMM: BM=128, BN=256, BK=32, 512 thr / 8 waves ----------------
// A single-bf16 [M][K] staged in LDS (16KB dbuf), m97-style 64B-granular chunks with
// XOR source-slot swizzle. B = pre-tiled weight split, read straight to VGPRs from L2.
template<bool POOL>
__global__ __launch_bounds__(512, 4)
void k_gemm_mfma(const u16* __restrict__ A, const u16* __restrict__ Bhi,
                 const u16* __restrict__ Blo,
                 const float* __restrict__ bias, u16* __restrict__ out_bf,
                 const int* __restrict__ batch, float* __restrict__ pool,
                 int M, int K) {
    __shared__ u16 ldsA[2][4096];   // 2 x 8KB: [128 rows][4 slots of 8 bf16]
    const int tid = threadIdx.x, lane = tid & 63, wid = tid >> 6;
    const int bm = blockIdx.x * 128;
    const int wr = (wid >> 2) * 64, wc = (wid & 3) * 64;
    const int lr = lane & 15, kg = lane >> 4;

    // per-wave A-stage addressing: wave wid stages rows wid*16..+15 (1KB chunk)
    const int srow = wid * 16 + (lane >> 2);            // local row 0..127
    const int sslot = lane & 3;
    const int ssw = (srow ^ (srow >> 2)) & 3;
    int srg = bm + srow; if (srg >= M) srg = M - 1;
    const u16* sbase = A + (size_t)srg * K + ((sslot ^ ssw) << 3);

    f32x4 acc[4][4];
#pragma unroll
    for (int i = 0; i < 4; ++i)
#pragma unroll
        for (int j = 0; j < 4; ++j) acc[i][j] = (f32x4){0.f, 0.f, 0.f, 0.f};

    const int nt = K >> 5;
    gll16(sbase, &ldsA[0][wid * 512]);     // prologue: stage tile 0
    __syncthreads();

    for (int t = 0; t < nt; ++t) {
        int cur = t & 1;
        if (t + 1 < nt)
            gll16(sbase + ((t + 1) << 5), &ldsA[cur ^ 1][wid * 512]);

        // B fragments straight from L2 (pre-tiled: contiguous 256B per 16-lane group)
        s16x8 bh[4], bl[4];
#pragma unroll
        for (int fn = 0; fn < 4; ++fn) {
            size_t off = ((size_t)((t << 2) + kg) * 256 + wc + fn * 16 + lr) * 8;
            bh[fn] = *(const s16x8*)&Bhi[off];
            bl[fn] = *(const s16x8*)&Blo[off];
        }
        // A fragments from LDS (swizzled slots)
        const u16* lb = ldsA[cur];
        s16x8 a[4];
#pragma unroll
        for (int fm = 0; fm < 4; ++fm) {
            int r = wr + fm * 16 + lr;
            a[fm] = *(const s16x8*)&lb[r * 32 + ((kg ^ ((r ^ (r >> 2)) & 3)) << 3)];
        }
#pragma unroll
        for (int fn = 0; fn < 4; ++fn)
#pragma unroll
            for (int fm = 0; fm < 4; ++fm) {
                acc[fm][fn] = __builtin_amdgcn_mfma_f32_16x16x32_bf16(a[fm], bh[fn], acc[fm][fn], 0, 0, 0);
                acc[fm][fn] = __builtin_amdgcn_mfma_f32_16x16x32_bf16(a[fm], bl[fn], acc[fm][fn], 0, 0, 0);
            }
        __syncthreads();
    }

    // epilogue: row = bm + wr + fm*16 + kg*4 + r ; col = wc + fn*16 + lr
#pragma unroll
    for (int fn = 0; fn < 4; ++fn) {
        int col = wc + fn * 16 + lr;
        float bv = bias[col];
        if (!POOL) {
#pragma unroll
            for (int fm = 0; fm < 4; ++fm) {
                int rbase = bm + wr + fm * 16 + kg * 4;
#pragma unroll
                for (int r = 0; r < 4; ++r) {
                    int row = rbase + r;
                    if (row < M)
                        out_bf[(size_t)row * 256 + col] = f2bf(fmaxf(acc[fm][fn][r] + bv, 0.f));
                }
            }
        } else {
            int gcur = -1;
            float run = 0.f;
#pragma unroll
            for (int fm = 0; fm < 4; ++fm) {
                int rbase = bm + wr + fm * 16 + kg * 4;
#pragma unroll
                for (int r = 0; r < 4; ++r) {
                    int row = rbase + r;
                    if (row < M) {
                        int g = batch[row];
                        float v = fmaxf(acc[fm][fn][r] + bv, 0.f);
                        if (g != gcur) {
                            if (gcur >= 0) atomicAdd(&pool[gcur * 256 + col], run);
                            gcur = g;
                            run = 0.f;
                        }
                        run += v;
                    }
                }
            }
            if (gcur >= 0) atomicAdd(&pool[gcur * 256 + col], run);
        }
    }
}

// ---------------- dense head ----------------
__global__ __launch_bounds__(128)
void k_dense(const float* __restrict__ sums, const float* __restrict__ counts,
             const float* __restrict__ W3, const float* __restrict__ b3,
             const float* __restrict__ W4, const float* __restrict__ b4,
             float* __restrict__ out) {
    __shared__ float g[256];
    __shared__ float hid[128];
    int gi = blockIdx.x;
    int t = threadIdx.x;
    float inv = 1.0f / fmaxf(counts[gi], 1.0f);
    for (int c = t; c < 256; c += 128) g[c] = sums[gi * 256 + c] * inv;
    __syncthreads();
    float acc = b3[t];
    for (int k = 0; k < 256; ++k) acc += g[k] * W3[k * 128 + t];
    hid[t] = fmaxf(acc, 0.0f);
    __syncthreads();
    if (t < 10) {
        float o = b4[t];
        for (int k = 0; k < 128; ++k) o += hid[k] * W4[k * 10 + t];
        out[gi * 10 + t] = o;
    }
}

extern "C" void kernel_launch(void* const* d_in, const int* in_sizes, int n_in,
                              void* d_out, int out_size, void* d_ws, size_t ws_size,
                              hipStream_t stream) {
    const float* x   = (const float*)d_in[0];
    const int*  eidx = (const int*)d_in[1];    // [2, NE]
    const int*  batch= (const int*)d_in[2];
    const float* W1 = (const float*)d_in[3];
    const float* b1 = (const float*)d_in[4];
    const float* W2 = (const float*)d_in[5];
    const float* b2 = (const float*)d_in[6];
    const float* W3 = (const float*)d_in[7];
    const float* b3 = (const float*)d_in[8];
    const float* W4 = (const float*)d_in[9];
    const float* b4 = (const float*)d_in[10];
    float* out = (float*)d_out;

    const int N = NN, E = NE, G = NG;
    const int* src = eidx;
    const int* dst = eidx + E;
    const int NB = (N + 255) / 256;

    // workspace layout (256B-aligned slices)
    char* p = (char*)d_ws;
    auto alloc = [&](size_t bytes) { char* r = p; p += (bytes + 255) & ~(size_t)255; return r; };
    u16*   h1bf   = (u16*)alloc((size_t)N * 256 * 2);   // bf16 h1 (gather source for conv2)
    u16*   xbf    = (u16*)alloc((size_t)N * 128 * 2);   // bf16 x  (gather source for conv1)
    float* dinv   = (float*)alloc((size_t)N * 4);
    float* sums   = (float*)alloc((size_t)G * 256 * 4);
    float* counts = (float*)alloc((size_t)G * 4);
    int*   cnt    = (int*)alloc((size_t)N * 4);         // reused as cursor after scan
    int*   rowptr = (int*)alloc((size_t)(N + 1) * 4);
    int*   bsum   = (int*)alloc((size_t)NB * 4);
    int*   csr    = (int*)alloc((size_t)E * 4);
    u16*   agg1   = (u16*)alloc((size_t)N * 128 * 2);   // bf16 aggregated x (GEMM1 A)
    u16*   agg2   = (u16*)alloc((size_t)N * 256 * 2);   // bf16 aggregated h1 (GEMM2 A)
    u16*   w1hi   = (u16*)alloc((size_t)256 * 128 * 2); // pre-tiled [kgrp][n][8]
    u16*   w1lo   = (u16*)alloc((size_t)256 * 128 * 2);
    u16*   w2hi   = (u16*)alloc((size_t)256 * 256 * 2);
    u16*   w2lo   = (u16*)alloc((size_t)256 * 256 * 2);
    int*   cursor = cnt;

    // fused preamble: xbf, tiled wsplits, zero sums, zero cnt, counts
    const int XB = (NN * 32 + 255) / 256;
    const int CB = (NN + 255) / 256;
    int pre_blocks = XB + 16 + 32 + 64 + CB + 1;
    k_preamble<<<pre_blocks, 256, 0, stream>>>(x, xbf, W1, w1hi, w1lo, W2, w2hi, w2lo,
                                               sums, cnt, batch, counts);

    // CSR build + dinv
    k_hist<<<(E + 255) / 256, 256, 0, stream>>>(dst, cnt, E);
    k_scan1<<<NB, 256, 0, stream>>>(cnt, bsum, N);
    k_scan2<<<1, 256, 0, stream>>>(bsum, NB);
    k_scan3<<<NB, 256, 0, stream>>>(cnt, bsum, rowptr, cursor, dinv, N);
    k_fill<<<(E + 255) / 256, 256, 0, stream>>>(src, dst, cursor, csr, E);

    // conv1: gather-aggregate xbf (128ch, 2 nodes/wave) -> bf16 A, GEMM K=128 -> h1bf
    k_agg_gather<128><<<(N + 7) / 8, 256, 0, stream>>>(rowptr, csr, dinv, xbf, agg1, N);
    int gblocks = (N + 127) / 128;
    k_gemm_mfma<false><<<gblocks, 512, 0, stream>>>(agg1, w1hi, w1lo, b1, h1bf,
                                                    nullptr, nullptr, N, 128);

    // conv2: gather-aggregate h1bf (256ch, 2 nodes/wave) -> bf16 A, GEMM K=256 + pool
    k_agg_gather<256><<<(N + 7) / 8, 256, 0, stream>>>(rowptr, csr, dinv, h1bf, agg2, N);
    k_gemm_mfma<true><<<gblocks, 512, 0, stream>>>(agg2, w2hi, w2lo, b2, nullptr,
                                                   batch, sums, N, 256);

    // dense head
    k_dense<<<G, 128, 0, stream>>>(sums, counts, W3, b3, W4, b4, out);
}